// Round 4
// baseline (185.942 us; speedup 1.0000x reference)
//
#include <hip/hip_runtime.h>
#include <math.h>

#define DEV __device__ __forceinline__

constexpr int Bb   = 2;
constexpr int Seq  = 1024;
constexpr int Dim  = 1024;
constexpr int Hh   = 8;
constexpr int Dh   = 64;
constexpr int Di   = 512;
constexpr int BN   = Bb * Seq;       // 2048
constexpr int NSEQ = Bb * Hh;        // 16
constexpr int CHUNK = 32;            // chunks per sequence
constexpr int CLEN  = Seq / CHUNK;   // 32
constexpr float EPSV = 1.1920929e-07f;
constexpr int NT2  = 8;              // conv timesteps per block (fused kernel)
constexpr int KSPL = 8;              // gate GEMM K-splits

typedef _Float16 half8 __attribute__((ext_vector_type(8)));
typedef float    f32x4 __attribute__((ext_vector_type(4)));

DEV float bf2f(unsigned short u) {
  union { unsigned int i; float f; } x; x.i = ((unsigned int)u) << 16; return x.f;
}
DEV unsigned short f2bf(float f) {
  union { float f; unsigned int i; } x; x.f = f;
  unsigned int r = x.i + 0x7fffu + ((x.i >> 16) & 1u);
  return (unsigned short)(r >> 16);
}
// flag: 1 -> fp32, 0 -> bf16
DEV float ldin(const void* p, int f32, size_t i) {
  if (f32) return ((const float*)p)[i];
  return bf2f(((const unsigned short*)p)[i]);
}
DEV void ld4(const void* p, int f32, size_t i, float* dst) {
  if (f32) {
    float4 u = *(const float4*)((const float*)p + i);
    dst[0] = u.x; dst[1] = u.y; dst[2] = u.z; dst[3] = u.w;
  } else {
    ushort4 u = *(const ushort4*)((const unsigned short*)p + i);
    dst[0] = bf2f(u.x); dst[1] = bf2f(u.y); dst[2] = bf2f(u.z); dst[3] = bf2f(u.w);
  }
}
// per-thread sample vote for self-sniff (call with tid<64, reduce in wave)
DEV int sniff_vote(const void* p, int n, int tid) {
  int j = 2 * tid, valid = 0, bad = 0;
  if (j < n) {
    valid = 1;
    float v = bf2f(((const unsigned short*)p)[j]);
    float a = fabsf(v);
    if (!(a >= 1e-12f && a <= 1e4f)) bad = 1;
  }
#pragma unroll
  for (int m = 1; m < 64; m <<= 1) { valid += __shfl_xor(valid, m); bad += __shfl_xor(bad, m); }
  return (2 * bad > valid) ? 1 : 0;
}

// async global->LDS: 16 bytes per lane, LDS dest = wave-uniform base + lane*16
DEV void gld16(const _Float16* g, _Float16* l) {
  __builtin_amdgcn_global_load_lds(
      (const __attribute__((address_space(1))) void*)g,
      (__attribute__((address_space(3))) void*)l, 16, 0, 0);
}

struct InPtrs { const void* p[17]; int n[17]; };

// ---------------------------------------------------------------------------
// K_FRONT: weight prep + fused RMSNorm/conv in one launch (independent roles).
// ---------------------------------------------------------------------------
__global__ __launch_bounds__(256) void k_front(
    InPtrs ip,
    int* __restrict__ flags,
    _Float16* __restrict__ wqT, _Float16* __restrict__ wkT,
    _Float16* __restrict__ wvT, _Float16* __restrict__ woT,
    _Float16* __restrict__ WgT,
    float* __restrict__ gqf, float* __restrict__ gkf, float* __restrict__ gbf,
    _Float16* __restrict__ xaf,
    _Float16* __restrict__ qc, _Float16* __restrict__ kc,
    _Float16* __restrict__ vc)
{
  int blk = blockIdx.x;
  int tid = threadIdx.x;
  __shared__ int sfl[8];
  __shared__ __align__(16) char smem_u[11 * Dim * 2];   // 22528 B union

  if (blk < 1024) {
    int z = blk >> 8, bx = blk & 15, by = (blk >> 4) & 15;
    int idx = (z == 0) ? 2 : ((z == 1) ? 3 : ((z == 2) ? 4 : 5));
    const void* src = ip.p[idx];
    _Float16* dst   = (z == 0) ? wqT : ((z == 1) ? wkT : ((z == 2) ? wvT : woT));
    int Kd = (z < 3) ? Dim : Di;
    int Nn = (z < 3) ? Di : Dim;
    int n0 = bx * 64, k0 = by * 64;
    if (n0 >= Nn || k0 >= Kd) return;

    if (tid < 64) { int f = sniff_vote(src, ip.n[idx], tid); if (tid == 0) sfl[0] = f; }
    __syncthreads();
    int f = sfl[0];

    float (*tile)[65] = (float(*)[65])smem_u;   // 64x65 floats = 16640 B
    int r = tid >> 4, c4 = (tid & 15) * 4;
#pragma unroll
    for (int rr = 0; rr < 4; ++rr) {
      int k = rr * 16 + r;
      ld4(src, f, (size_t)(k0 + k) * Nn + n0 + c4, &tile[k][c4]);
    }
    __syncthreads();
#pragma unroll
    for (int rr = 0; rr < 4; ++rr) {
      int n = rr * 16 + r;
      _Float16 o4[4];
#pragma unroll
      for (int j = 0; j < 4; ++j) o4[j] = (_Float16)tile[c4 + j][n];
      *(ushort4*)&dst[(size_t)(n0 + n) * Kd + k0 + c4] = *(ushort4*)o4;
    }
  } else if (blk < 1088) {
    int row = blk - 1024;   // 0..63
    if (row < 24) {
      int g = row >> 3, h = row & 7;
      int idx = (g == 0) ? 11 : ((g == 1) ? 13 : 15);
      const void* W = ip.p[idx];
      if (tid < 64) { int f = sniff_vote(W, ip.n[idx], tid); if (tid == 0) sfl[0] = f; }
      __syncthreads();
      int f = sfl[0];
#pragma unroll
      for (int it = 0; it < 4; ++it) {
        int d = it * 256 + tid;
        WgT[(size_t)row * Dim + d] = (_Float16)ldin(W, f, (size_t)d * Hh + h);
      }
    } else {
#pragma unroll
      for (int it = 0; it < 4; ++it)
        WgT[(size_t)row * Dim + it * 256 + tid] = (_Float16)0.f;
    }
  } else if (blk == 1088) {
    __shared__ int allf[17];
    for (int ii = 0; ii < 17; ++ii) {
      if (tid < 64) {
        int f = sniff_vote(ip.p[ii], ip.n[ii], tid);
        if (tid == 0) { flags[ii] = f; allf[ii] = f; }
      }
    }
    __syncthreads();
    int f9 = allf[9], f10 = allf[10];
    for (int i = tid; i < Di; i += 256) {
      gqf[i] = ldin(ip.p[9], f9, i);
      gkf[i] = ldin(ip.p[10], f10, i);
    }
    if (tid < 24) {
      int g = tid >> 3, h = tid & 7;
      int idx = (g == 0) ? 12 : ((g == 1) ? 14 : 16);
      gbf[tid] = ldin(ip.p[idx], allf[idx], h);
    }
  } else {
    // ---- rmsnorm + depthwise conv (self-contained) ----
    constexpr int NR = NT2 + 3;   // 11 rows: t0-2 .. t0+NT2
    _Float16 (*xas)[Dim] = (_Float16(*)[Dim])smem_u;

    int rb = blk - 1089;
    int tb = rb & 127, b = rb >> 7;
    int t0 = tb * NT2;
    int lane = tid & 63, wv = tid >> 6;

    if (tid < 64) {
      int f0 = sniff_vote(ip.p[0], ip.n[0], tid);
      int f1 = sniff_vote(ip.p[1], ip.n[1], tid);
      int f6 = sniff_vote(ip.p[6], ip.n[6], tid);
      int f7 = sniff_vote(ip.p[7], ip.n[7], tid);
      int f8 = sniff_vote(ip.p[8], ip.n[8], tid);
      if (tid == 0) { sfl[0] = f0; sfl[1] = f1; sfl[2] = f6; sfl[3] = f7; sfl[4] = f8; }
    }
    __syncthreads();
    int fx = sfl[0], fw = sfl[1], f6 = sfl[2], f7 = sfl[3], f8 = sfl[4];
    int e0 = lane * 16;

    float wr[16];
#pragma unroll
    for (int q = 0; q < 4; ++q) ld4(ip.p[1], fw, e0 + q * 4, &wr[q * 4]);

    for (int rr = wv; rr < NR; rr += 4) {
      int r = t0 - 2 + rr;
      float xv[16];
      bool inr = (r >= 0 && r < Seq);
      if (inr) {
        size_t rbx = (size_t)(b * Seq + r) * Dim + e0;
#pragma unroll
        for (int q = 0; q < 4; ++q) ld4(ip.p[0], fx, rbx + q * 4, &xv[q * 4]);
      } else {
#pragma unroll
        for (int j = 0; j < 16; ++j) xv[j] = 0.f;
      }
      float ss = 0.f;
#pragma unroll
      for (int j = 0; j < 16; ++j) ss = fmaf(xv[j], xv[j], ss);
#pragma unroll
      for (int m = 1; m < 64; m <<= 1) ss += __shfl_xor(ss, m);
      float scale = rsqrtf(ss * (1.0f / Dim) + EPSV);

      _Float16 o[16];
#pragma unroll
      for (int j = 0; j < 16; ++j) o[j] = (_Float16)(xv[j] * scale * wr[j]);
      *(uint4*)&xas[rr][e0]     = *(uint4*)&o[0];
      *(uint4*)&xas[rr][e0 + 8] = *(uint4*)&o[8];
      if (inr && r >= t0 && r < t0 + NT2) {
        size_t ob = (size_t)(b * Seq + r) * Dim + e0;
        *(uint4*)&xaf[ob]     = *(uint4*)&o[0];
        *(uint4*)&xaf[ob + 8] = *(uint4*)&o[8];
      }
    }
    __syncthreads();

    int c0 = tid * 4;
    float lwq[16], lwk[16], lwv[16];
#pragma unroll
    for (int q = 0; q < 4; ++q) {
      ld4(ip.p[6], f6, (size_t)c0 * 4 + q * 4, &lwq[q * 4]);
      ld4(ip.p[7], f7, (size_t)c0 * 4 + q * 4, &lwk[q * 4]);
      ld4(ip.p[8], f8, (size_t)c0 * 4 + q * 4, &lwv[q * 4]);
    }

#pragma unroll
    for (int tt = 0; tt < NT2; ++tt) {
      float rv[4][4];
#pragma unroll
      for (int k = 0; k < 4; ++k) {
        _Float16 hx[4];
        *(ushort4*)hx = *(const ushort4*)&xas[tt + k][c0];
#pragma unroll
        for (int j = 0; j < 4; ++j) rv[k][j] = (float)hx[j];
      }
      _Float16 tq[4], tk[4], tv[4];
#pragma unroll
      for (int j = 0; j < 4; ++j) {
        float aq = rv[0][j] * lwq[j * 4 + 0] + rv[1][j] * lwq[j * 4 + 1]
                 + rv[2][j] * lwq[j * 4 + 2] + rv[3][j] * lwq[j * 4 + 3];
        float ak = rv[0][j] * lwk[j * 4 + 0] + rv[1][j] * lwk[j * 4 + 1]
                 + rv[2][j] * lwk[j * 4 + 2] + rv[3][j] * lwk[j * 4 + 3];
        float av = rv[0][j] * lwv[j * 4 + 0] + rv[1][j] * lwv[j * 4 + 1]
                 + rv[2][j] * lwv[j * 4 + 2] + rv[3][j] * lwv[j * 4 + 3];
        tq[j] = (_Float16)aq; tk[j] = (_Float16)ak; tv[j] = (_Float16)av;
      }
      size_t o = ((size_t)(b * Seq + t0 + tt)) * Dim + c0;
      *(ushort4*)&qc[o] = *(ushort4*)tq;
      *(ushort4*)&kc[o] = *(ushort4*)tk;
      *(ushort4*)&vc[o] = *(ushort4*)tv;
    }
  }
}

// ---------------------------------------------------------------------------
// Shared 128M x 64N GEMM tile body (gld16 staging), f16 epilogue.
// ---------------------------------------------------------------------------
DEV void gemm_tile_12864_f16(
    const _Float16* __restrict__ A, const _Float16* __restrict__ Bt,
    _Float16* __restrict__ C, int Nn, int Kd, int m0, int n0,
    _Float16* Asl, _Float16* Bsl, int tid)
{
  int lane = tid & 63, wv = tid >> 6;
  int mrow = lane & 15, quad = lane >> 4;
  int wm = wv * 32;
  int sr = lane >> 2, sc = (lane & 3) * 8;

  f32x4 acc[2][4];
#pragma unroll
  for (int mi = 0; mi < 2; ++mi)
#pragma unroll
    for (int ni = 0; ni < 4; ++ni) acc[mi][ni] = (f32x4){0.f, 0.f, 0.f, 0.f};

  for (int kt = 0; kt < Kd; kt += 32) {
    __syncthreads();
    gld16(&A [(size_t)(m0 + wv * 32      + sr) * Kd + kt + sc], &Asl[(wv * 32     ) * 32]);
    gld16(&A [(size_t)(m0 + wv * 32 + 16 + sr) * Kd + kt + sc], &Asl[(wv * 32 + 16) * 32]);
    gld16(&Bt[(size_t)(n0 + wv * 16      + sr) * Kd + kt + sc], &Bsl[(wv * 16     ) * 32]);
    __syncthreads();

    half8 bfr[4];
#pragma unroll
    for (int ni = 0; ni < 4; ++ni)
      bfr[ni] = *(const half8*)&Bsl[(ni * 16 + mrow) * 32 + quad * 8];
#pragma unroll
    for (int mi = 0; mi < 2; ++mi) {
      half8 afr = *(const half8*)&Asl[(wm + mi * 16 + mrow) * 32 + quad * 8];
#pragma unroll
      for (int ni = 0; ni < 4; ++ni)
        acc[mi][ni] = __builtin_amdgcn_mfma_f32_16x16x32_f16(afr, bfr[ni], acc[mi][ni], 0, 0, 0);
    }
  }

#pragma unroll
  for (int mi = 0; mi < 2; ++mi) {
#pragma unroll
    for (int ni = 0; ni < 4; ++ni) {
      int col = n0 + ni * 16 + mrow;
#pragma unroll
      for (int r2 = 0; r2 < 4; ++r2) {
        int row = m0 + wm + mi * 16 + quad * 4 + r2;
        C[(size_t)row * Nn + col] = (_Float16)acc[mi][ni][r2];
      }
    }
  }
}

// ---------------------------------------------------------------------------
// K_MID: QKV MFMA GEMM (128x64 tiles, 384 blocks) + gate GEMM partials (256).
// ---------------------------------------------------------------------------
__global__ __launch_bounds__(256) void k_mid(
    const _Float16* __restrict__ qc, const _Float16* __restrict__ kc,
    const _Float16* __restrict__ vc,
    const _Float16* __restrict__ wqT, const _Float16* __restrict__ wkT,
    const _Float16* __restrict__ wvT,
    const _Float16* __restrict__ xaf, const _Float16* __restrict__ WgT,
    _Float16* __restrict__ qpre, _Float16* __restrict__ kpre,
    _Float16* __restrict__ vpre,
    float* __restrict__ gpart)
{
  __shared__ __align__(16) _Float16 ldsbuf[256 * 32];   // 16 KB

  int blk = blockIdx.x;
  int tid = threadIdx.x, lane = tid & 63, wv = tid >> 6;
  int mrow = lane & 15, quad = lane >> 4;

  if (blk < 384) {
    int z = blk >> 7, rem = blk & 127;       // 128 tiles per matrix: 16 M x 8 N
    int by = rem >> 3, bx = rem & 7;
    const _Float16* A  = (z == 0) ? qc : ((z == 1) ? kc : vc);
    const _Float16* Bt = (z == 0) ? wqT : ((z == 1) ? wkT : wvT);
    _Float16* C        = (z == 0) ? qpre : ((z == 1) ? kpre : vpre);
    gemm_tile_12864_f16(A, Bt, C, Di, Dim, by * 128, bx * 64,
                        ldsbuf, ldsbuf + 128 * 32, tid);
  } else {
    _Float16 (*As)[40] = (_Float16(*)[40])ldsbuf;
    _Float16 (*Bs)[40] = (_Float16(*)[40])(ldsbuf + 128 * 40);

    int g = blk - 384;
    int m0 = (g & 31) * 64, ks = g >> 5;
    int srow = tid >> 2, scol = (tid & 3) * 8;
    int kbase = ks * (Dim / KSPL);

    f32x4 acc[4];
#pragma unroll
    for (int mi = 0; mi < 4; ++mi) acc[mi] = (f32x4){0.f, 0.f, 0.f, 0.f};

    for (int kt = kbase; kt < kbase + Dim / KSPL; kt += 32) {
      __syncthreads();
      *(uint4*)&As[srow][scol] = *(const uint4*)&xaf[(size_t)(m0 + srow) * Dim + kt + scol];
      *(uint4*)&Bs[srow][scol] = *(const uint4*)&WgT[(size_t)srow * Dim + kt + scol];
      __syncthreads();
      half8 bfr = *(const half8*)&Bs[wv * 16 + mrow][quad * 8];
#pragma unroll
      for (int mi = 0; mi < 4; ++mi) {
        half8 afr = *(const half8*)&As[mi * 16 + mrow][quad * 8];
        acc[mi] = __builtin_amdgcn_mfma_f32_16x16x32_f16(afr, bfr, acc[mi], 0, 0, 0);
      }
    }

    int col = wv * 16 + mrow;          // only 0..23 real
    if (col < 24) {
#pragma unroll
      for (int mi = 0; mi < 4; ++mi) {
#pragma unroll
        for (int r2 = 0; r2 < 4; ++r2) {
          int row = m0 + mi * 16 + quad * 4 + r2;
          gpart[((size_t)ks * BN + row) * 32 + col] = acc[mi][r2];
        }
      }
    }
  }
}

// ---------------------------------------------------------------------------
// K3: final MFMA GEMM, 128M x 64N, global_load_lds staging, epilogue by flags.
// ---------------------------------------------------------------------------
__global__ __launch_bounds__(256) void k_gemm_fin(
    const _Float16* __restrict__ A, const _Float16* __restrict__ Bt,
    void* __restrict__ C, const int* __restrict__ flags, int Nn, int Kd)
{
  __shared__ __align__(16) _Float16 lds[(128 + 64) * 32];   // 12 KB
  _Float16* Asl = lds;                // [128][32] linear
  _Float16* Bsl = lds + 128 * 32;     // [64][32] linear

  int tid = threadIdx.x, lane = tid & 63, wv = tid >> 6;
  int n0 = blockIdx.x * 64, m0 = blockIdx.y * 128;
  int mrow = lane & 15, quad = lane >> 4;
  int wm = wv * 32;
  int sr = lane >> 2, sc = (lane & 3) * 8;

  f32x4 acc[2][4];
#pragma unroll
  for (int mi = 0; mi < 2; ++mi)
#pragma unroll
    for (int ni = 0; ni < 4; ++ni) acc[mi][ni] = (f32x4){0.f, 0.f, 0.f, 0.f};

  for (int kt = 0; kt < Kd; kt += 32) {
    __syncthreads();
    gld16(&A [(size_t)(m0 + wv * 32      + sr) * Kd + kt + sc], &Asl[(wv * 32     ) * 32]);
    gld16(&A [(size_t)(m0 + wv * 32 + 16 + sr) * Kd + kt + sc], &Asl[(wv * 32 + 16) * 32]);
    gld16(&Bt[(size_t)(n0 + wv * 16      + sr) * Kd + kt + sc], &Bsl[(wv * 16     ) * 32]);
    __syncthreads();

    half8 bfr[4];
#pragma unroll
    for (int ni = 0; ni < 4; ++ni)
      bfr[ni] = *(const half8*)&Bsl[(ni * 16 + mrow) * 32 + quad * 8];
#pragma unroll
    for (int mi = 0; mi < 2; ++mi) {
      half8 afr = *(const half8*)&Asl[(wm + mi * 16 + mrow) * 32 + quad * 8];
#pragma unroll
      for (int ni = 0; ni < 4; ++ni)
        acc[mi][ni] = __builtin_amdgcn_mfma_f32_16x16x32_f16(afr, bfr[ni], acc[mi][ni], 0, 0, 0);
    }
  }

  int any_bf16 = 0;
#pragma unroll
  for (int i2 = 0; i2 < 17; ++i2) any_bf16 |= (flags[i2] == 0);

#pragma unroll
  for (int mi = 0; mi < 2; ++mi) {
#pragma unroll
    for (int ni = 0; ni < 4; ++ni) {
      int col = n0 + ni * 16 + mrow;
#pragma unroll
      for (int r2 = 0; r2 < 4; ++r2) {
        int row = m0 + wm + mi * 16 + quad * 4 + r2;
        float v = acc[mi][ni][r2];
        size_t idx = (size_t)row * Nn + col;
        if (any_bf16) ((unsigned short*)C)[idx] = f2bf(v);
        else          ((float*)C)[idx] = v;
      }
    }
  }
}

// ---------------------------------------------------------------------------
// Gate preload helper: reduce KSPL partials + bias + sigmoid (96 threads)
// ---------------------------------------------------------------------------
DEV void load_gates(const float* __restrict__ gpart, const float* __restrict__ gbf,
                    int b, int h, int c, int tid,
                    float* gl, float* gd, float* gm)
{
  if (tid < 96) {
    int which = tid >> 5, t2 = tid & 31;
    int col = which * 8 + h;
    int row = b * Seq + c * CLEN + t2;
    float acc = gbf[col];
#pragma unroll
    for (int ks = 0; ks < KSPL; ++ks)
      acc += gpart[((size_t)ks * BN + row) * 32 + col];
    float sg = 1.f / (1.f + expf(-acc));
    if (which == 0) gl[t2] = sg; else if (which == 1) gd[t2] = sg; else gm[t2] = sg;
  }
}

// ---------------------------------------------------------------------------
// K_PHASEA: local chunk recurrence + (new) local retrieval part.
//   - normalizes k (LDS only) and q (written back to qpre for phaseC)
//   - computes Zl/Sl chunk outputs -> ZS
//   - computes u_t = Sl_{t-1} . q_t  -> ub  and (Dcum,wacc)_{t-1} -> ab
//   y_t = u_t + a_t*(S_in q_t) + b_t*(Z_in q_t) is finished by phaseC.
// ---------------------------------------------------------------------------
__global__ __launch_bounds__(256) void k_phaseA(
    const _Float16* __restrict__ kpre, const _Float16* __restrict__ vpre,
    _Float16* __restrict__ qpre,
    const float* __restrict__ gkf, const float* __restrict__ gqf,
    const float* __restrict__ gpart, const float* __restrict__ gbf,
    _Float16* __restrict__ ZS_Z, _Float16* __restrict__ ZS_S,
    float* __restrict__ Mc, float* __restrict__ Dc, float* __restrict__ Wc,
    float* __restrict__ ub, float* __restrict__ ab)
{
  int c = blockIdx.x, s = blockIdx.y;
  int b = s >> 3, h = s & 7;
  int tid = threadIdx.x, lane = tid & 63, wv = tid >> 6;
  int i = tid >> 2, j0 = (tid & 3) * 16;
  int sc_ = s * CHUNK + c;
  __shared__ float kn[CLEN][64], vv[CLEN][64], qn[CLEN][64];
  __shared__ float gl[CLEN], gd[CLEN], gm[CLEN];

  {
    int t = tid >> 3, col = (tid & 7) * 8;
    size_t g = ((size_t)(b * Seq + c * CLEN + t)) * Di + h * 64 + col;
    half8 kv = *(const half8*)&kpre[g];
    half8 vvv = *(const half8*)&vpre[g];
    half8 qv = *(const half8*)&qpre[g];
#pragma unroll
    for (int j = 0; j < 8; ++j) {
      kn[t][col + j] = (float)kv[j]; vv[t][col + j] = (float)vvv[j];
      qn[t][col + j] = (float)qv[j];
    }
    load_gates(gpart, gbf, b, h, c, tid, gl, gd, gm);
  }
  __syncthreads();
  {
    float gk = gkf[h * 64 + lane];
    float gq = gqf[h * 64 + lane];
#pragma unroll
    for (int tt = 0; tt < 8; ++tt) {
      int t = wv * 8 + tt;
      float kvv = kn[t][lane];
      float ssk = kvv * kvv;
      float qvv = qn[t][lane];
      float ssq = qvv * qvv;
#pragma unroll
      for (int m = 1; m < 64; m <<= 1) { ssk += __shfl_xor(ssk, m); ssq += __shfl_xor(ssq, m); }
      kn[t][lane] = kvv * (1.f / fmaxf(sqrtf(ssk) * 0.125f, 1e-8f)) * gk;
      float qnv = qvv * (1.f / fmaxf(sqrtf(ssq) * 0.125f, 1e-8f)) * gq;
      qn[t][lane] = qnv;
      // write normalized q back so phaseC skips the norm pass
      qpre[((size_t)(b * Seq + c * CLEN + t)) * Di + h * 64 + lane] = (_Float16)qnv;
    }
  }
  __syncthreads();

  float Zl[16], Sl[16];
#pragma unroll
  for (int jj = 0; jj < 16; ++jj) { Zl[jj] = 0.f; Sl[jj] = 0.f; }
  float Mcum = 1.f, Dcum = 1.f, wacc = 0.f;
  float Dprev = 1.f, wprev = 0.f;

  for (int t = 0; t < CLEN; ++t) {
    float l = gl[t], dd = gd[t], mm = gm[t];

    // local retrieval part: u_t = Sl_{t-1} . q_t, plus coefficient save
    float up = 0.f;
#pragma unroll
    for (int jj = 0; jj < 16; ++jj)
      up = fmaf(Sl[jj], qn[t][j0 + jj], up);
    up += __shfl_xor(up, 1);
    up += __shfl_xor(up, 2);
    if ((tid & 3) == 0) ub[((size_t)sc_ * CLEN + t) * 64 + i] = up;
    if (tid == 0) ab[(size_t)sc_ * 64 + t * 2]     = Dprev;
    if (tid == 1) ab[(size_t)sc_ * 64 + t * 2 + 1] = wprev;

    float vi = vv[t][i];
    Mcum *= mm;
#pragma unroll
    for (int jj = 0; jj < 16; ++jj) {
      Zl[jj] = fmaf(mm, Zl[jj], -vi * kn[t][j0 + jj]);
      Sl[jj] = fmaf(dd, Sl[jj], -l * Zl[jj]);
    }
    wacc = fmaf(dd, wacc, -l * Mcum);
    Dcum *= dd;
    Dprev = Dcum; wprev = wacc;
  }
  size_t base = ((size_t)sc_) * 4096 + (size_t)i * 64 + j0;
  half8 zo0, zo1, so0, so1;
#pragma unroll
  for (int jj = 0; jj < 8; ++jj) {
    zo0[jj] = (_Float16)Zl[jj];     zo1[jj] = (_Float16)Zl[jj + 8];
    so0[jj] = (_Float16)Sl[jj];     so1[jj] = (_Float16)Sl[jj + 8];
  }
  *(half8*)&ZS_Z[base] = zo0; *(half8*)&ZS_Z[base + 8] = zo1;
  *(half8*)&ZS_S[base] = so0; *(half8*)&ZS_S[base + 8] = so1;
  if (tid == 0) {
    Mc[sc_] = Mcum; Dc[sc_] = Dcum; Wc[sc_] = wacc;
  }
}

__global__ __launch_bounds__(256) void k_phaseB(
    _Float16* __restrict__ ZS_Z, _Float16* __restrict__ ZS_S,
    const float* __restrict__ Mc, const float* __restrict__ Dc,
    const float* __restrict__ Wc)
{
  int s = blockIdx.x;
  int e = blockIdx.y * 256 + threadIdx.x;
  float Z = 0.f, S = 0.f;
  for (int c = 0; c < CHUNK; ++c) {
    size_t base = ((size_t)(s * CHUNK + c)) * 4096 + e;
    float mc = Mc[s * CHUNK + c], dc = Dc[s * CHUNK + c], wc = Wc[s * CHUNK + c];
    float zl = (float)ZS_Z[base], sl = (float)ZS_S[base];
    ZS_Z[base] = (_Float16)Z; ZS_S[base] = (_Float16)S;   // chunk inputs
    S = fmaf(dc, S, fmaf(wc, Z, sl));  // uses OLD Z (= chunk input)
    Z = fmaf(mc, Z, zl);
  }
}

// ---------------------------------------------------------------------------
// K_PHASEC (lightweight): y_t = u_t + a_t*(S_in q_t) + b_t*(Z_in q_t).
// No k/v staging, no gates, no local recurrence.
// ---------------------------------------------------------------------------
__global__ __launch_bounds__(256) void k_phaseC(
    const _Float16* __restrict__ qpre,
    const _Float16* __restrict__ ZS_Z, const _Float16* __restrict__ ZS_S,
    const float* __restrict__ ub, const float* __restrict__ ab,
    _Float16* __restrict__ yb)
{
  int c = blockIdx.x, s = blockIdx.y;
  int b = s >> 3, h = s & 7;
  int tid = threadIdx.x;
  int i = tid >> 2, j0 = (tid & 3) * 16;
  int sc_ = s * CHUNK + c;
  __shared__ float qn[CLEN][64];
  __shared__ float abs_[64];

  float Zi_[16], Si_[16];
  size_t base = ((size_t)sc_) * 4096 + (size_t)i * 64 + j0;
  {
    half8 z0 = *(const half8*)&ZS_Z[base], z1 = *(const half8*)&ZS_Z[base + 8];
    half8 s0 = *(const half8*)&ZS_S[base], s1 = *(const half8*)&ZS_S[base + 8];
#pragma unroll
    for (int jj = 0; jj < 8; ++jj) {
      Zi_[jj] = (float)z0[jj]; Zi_[jj + 8] = (float)z1[jj];
      Si_[jj] = (float)s0[jj]; Si_[jj + 8] = (float)s1[jj];
    }
  }
  {
    int t = tid >> 3, col = (tid & 7) * 8;
    size_t g = ((size_t)(b * Seq + c * CLEN + t)) * Di + h * 64 + col;
    half8 qv = *(const half8*)&qpre[g];   // already normalized (phaseA)
#pragma unroll
    for (int j = 0; j < 8; ++j) qn[t][col + j] = (float)qv[j];
    if (tid < 64) abs_[tid] = ab[(size_t)sc_ * 64 + tid];
  }
  __syncthreads();

  for (int t = 0; t < CLEN; ++t) {
    float sq = 0.f, zq = 0.f;
#pragma unroll
    for (int jj = 0; jj < 16; ++jj) {
      float q = qn[t][j0 + jj];
      sq = fmaf(Si_[jj], q, sq);
      zq = fmaf(Zi_[jj], q, zq);
    }
    sq += __shfl_xor(sq, 1); sq += __shfl_xor(sq, 2);
    zq += __shfl_xor(zq, 1); zq += __shfl_xor(zq, 2);
    if ((tid & 3) == 0) {
      float a = abs_[t * 2], bb2 = abs_[t * 2 + 1];
      float y = ub[((size_t)sc_ * CLEN + t) * 64 + i] + a * sq + bb2 * zq;
      yb[((size_t)(b * Seq + c * CLEN + t)) * Di + h * 64 + i] = (_Float16)y;
    }
  }
}

// ---------------------------------------------------------------------------
extern "C" void kernel_launch(void* const* d_in, const int* in_sizes, int n_in,
                              void* d_out, int out_size, void* d_ws, size_t ws_size,
                              hipStream_t stream) {
  InPtrs ip;
  for (int i = 0; i < 17; ++i) { ip.p[i] = d_in[i]; ip.n[i] = in_sizes[i]; }

  char* p = (char*)d_ws;
  auto take = [&](size_t bytes) -> char* {
    char* q = p; p += (bytes + 255) & ~(size_t)255; return q;
  };
  int* flags           = (int*)take(32 * 4);
  _Float16* xaf        = (_Float16*)take((size_t)BN * Dim * 2);   // 4 MB
  _Float16* qc         = (_Float16*)take((size_t)BN * Dim * 2);   // 4 MB
  _Float16* kc         = (_Float16*)take((size_t)BN * Dim * 2);   // 4 MB
  _Float16* vc         = (_Float16*)take((size_t)BN * Dim * 2);   // 4 MB
  _Float16* qpre       = (_Float16*)take((size_t)BN * Di * 2);    // 2 MB
  _Float16* kpre       = (_Float16*)take((size_t)BN * Di * 2);    // 2 MB
  _Float16* vpre       = (_Float16*)take((size_t)BN * Di * 2);    // 2 MB
  float* gpart         = (float*)take((size_t)KSPL * BN * 32 * 4); // 2 MB
  float* Mc            = (float*)take((size_t)NSEQ * CHUNK * 4);
  float* Dc            = (float*)take((size_t)NSEQ * CHUNK * 4);
  float* Wc            = (float*)take((size_t)NSEQ * CHUNK * 4);
  float* ub            = (float*)take((size_t)NSEQ * CHUNK * CLEN * 64 * 4); // 4 MB
  float* ab            = (float*)take((size_t)NSEQ * CHUNK * 64 * 4);        // 128 KB
  _Float16* wqT        = (_Float16*)take((size_t)Di * Dim * 2);   // 1 MB
  _Float16* wkT        = (_Float16*)take((size_t)Di * Dim * 2);   // 1 MB
  _Float16* wvT        = (_Float16*)take((size_t)Di * Dim * 2);   // 1 MB
  _Float16* woT        = (_Float16*)take((size_t)Dim * Di * 2);   // 1 MB
  _Float16* WgT        = (_Float16*)take((size_t)64 * Dim * 2);   // 128 KB
  float* gqf           = (float*)take(Di * 4);
  float* gkf           = (float*)take(Di * 4);
  float* gbf           = (float*)take(32 * 4);
  // Aliases: qc/kc/vc are dead after k_mid
  _Float16* ZS_Z       = qc;
  _Float16* ZS_S       = kc;
  _Float16* yb         = vc;

  k_front<<<1345, 256, 0, stream>>>(ip, flags, wqT, wkT, wvT, woT, WgT,
                                    gqf, gkf, gbf, xaf, qc, kc, vc);

  k_mid<<<640, 256, 0, stream>>>(qc, kc, vc, wqT, wkT, wvT, xaf, WgT,
                                 qpre, kpre, vpre, gpart);

  k_phaseA<<<dim3(CHUNK, NSEQ), 256, 0, stream>>>(kpre, vpre, qpre, gkf, gqf,
                                                  gpart, gbf,
                                                  ZS_Z, ZS_S, Mc, Dc, Wc,
                                                  ub, ab);
  k_phaseB<<<dim3(NSEQ, 16), 256, 0, stream>>>(ZS_Z, ZS_S, Mc, Dc, Wc);
  k_phaseC<<<dim3(CHUNK, NSEQ), 256, 0, stream>>>(qpre, ZS_Z, ZS_S, ub, ab, yb);

  k_gemm_fin<<<dim3(Dim / 64, BN / 128), 256, 0, stream>>>(
      yb, woT, d_out, flags, Dim, Di);
}

// Round 5
// 179.448 us; speedup vs baseline: 1.0362x; 1.0362x over previous
//
#include <hip/hip_runtime.h>
#include <math.h>

#define DEV __device__ __forceinline__

constexpr int Bb   = 2;
constexpr int Seq  = 1024;
constexpr int Dim  = 1024;
constexpr int Hh   = 8;
constexpr int Dh   = 64;
constexpr int Di   = 512;
constexpr int BN   = Bb * Seq;       // 2048
constexpr int NSEQ = Bb * Hh;        // 16
constexpr int CHUNK = 32;            // chunks per sequence
constexpr int CLEN  = Seq / CHUNK;   // 32
constexpr float EPSV = 1.1920929e-07f;
constexpr int NT2  = 8;              // conv timesteps per block (fused kernel)
constexpr int KSPL = 8;              // gate GEMM K-splits

typedef _Float16 half8 __attribute__((ext_vector_type(8)));
typedef float    f32x4 __attribute__((ext_vector_type(4)));

DEV float bf2f(unsigned short u) {
  union { unsigned int i; float f; } x; x.i = ((unsigned int)u) << 16; return x.f;
}
DEV unsigned short f2bf(float f) {
  union { float f; unsigned int i; } x; x.f = f;
  unsigned int r = x.i + 0x7fffu + ((x.i >> 16) & 1u);
  return (unsigned short)(r >> 16);
}
// flag: 1 -> fp32, 0 -> bf16
DEV float ldin(const void* p, int f32, size_t i) {
  if (f32) return ((const float*)p)[i];
  return bf2f(((const unsigned short*)p)[i]);
}
DEV void ld4(const void* p, int f32, size_t i, float* dst) {
  if (f32) {
    float4 u = *(const float4*)((const float*)p + i);
    dst[0] = u.x; dst[1] = u.y; dst[2] = u.z; dst[3] = u.w;
  } else {
    ushort4 u = *(const ushort4*)((const unsigned short*)p + i);
    dst[0] = bf2f(u.x); dst[1] = bf2f(u.y); dst[2] = bf2f(u.z); dst[3] = bf2f(u.w);
  }
}
// per-thread sample vote for self-sniff (call with tid<64, reduce in wave)
DEV int sniff_vote(const void* p, int n, int tid) {
  int j = 2 * tid, valid = 0, bad = 0;
  if (j < n) {
    valid = 1;
    float v = bf2f(((const unsigned short*)p)[j]);
    float a = fabsf(v);
    if (!(a >= 1e-12f && a <= 1e4f)) bad = 1;
  }
#pragma unroll
  for (int m = 1; m < 64; m <<= 1) { valid += __shfl_xor(valid, m); bad += __shfl_xor(bad, m); }
  return (2 * bad > valid) ? 1 : 0;
}

// async global->LDS: 16 bytes per lane, LDS dest = wave-uniform base + lane*16
DEV void gld16(const _Float16* g, _Float16* l) {
  __builtin_amdgcn_global_load_lds(
      (const __attribute__((address_space(1))) void*)g,
      (__attribute__((address_space(3))) void*)l, 16, 0, 0);
}

struct InPtrs { const void* p[17]; int n[17]; };

// ---------------------------------------------------------------------------
// K_FRONT: weight prep + fused RMSNorm/conv in one launch (independent roles).
//   [0,1024)    : transpose+convert wq/wk/wv/wo -> f16 [N][K]
//   [1024,1088) : gate weights -> WgT[64][1024]
//   1088        : full flags[17] + gammas + gate biases
//   [1089,1345) : rmsnorm+conv blocks (self-sniffed, raw conv weights)
// ---------------------------------------------------------------------------
__global__ __launch_bounds__(256) void k_front(
    InPtrs ip,
    int* __restrict__ flags,
    _Float16* __restrict__ wqT, _Float16* __restrict__ wkT,
    _Float16* __restrict__ wvT, _Float16* __restrict__ woT,
    _Float16* __restrict__ WgT,
    float* __restrict__ gqf, float* __restrict__ gkf, float* __restrict__ gbf,
    _Float16* __restrict__ xaf,
    _Float16* __restrict__ qc, _Float16* __restrict__ kc,
    _Float16* __restrict__ vc)
{
  int blk = blockIdx.x;
  int tid = threadIdx.x;
  __shared__ int sfl[8];
  __shared__ __align__(16) char smem_u[11 * Dim * 2];   // 22528 B union

  if (blk < 1024) {
    int z = blk >> 8, bx = blk & 15, by = (blk >> 4) & 15;
    int idx = (z == 0) ? 2 : ((z == 1) ? 3 : ((z == 2) ? 4 : 5));
    const void* src = ip.p[idx];
    _Float16* dst   = (z == 0) ? wqT : ((z == 1) ? wkT : ((z == 2) ? wvT : woT));
    int Kd = (z < 3) ? Dim : Di;
    int Nn = (z < 3) ? Di : Dim;
    int n0 = bx * 64, k0 = by * 64;
    if (n0 >= Nn || k0 >= Kd) return;

    if (tid < 64) { int f = sniff_vote(src, ip.n[idx], tid); if (tid == 0) sfl[0] = f; }
    __syncthreads();
    int f = sfl[0];

    float (*tile)[65] = (float(*)[65])smem_u;   // 64x65 floats = 16640 B
    int r = tid >> 4, c4 = (tid & 15) * 4;
#pragma unroll
    for (int rr = 0; rr < 4; ++rr) {
      int k = rr * 16 + r;
      ld4(src, f, (size_t)(k0 + k) * Nn + n0 + c4, &tile[k][c4]);
    }
    __syncthreads();
#pragma unroll
    for (int rr = 0; rr < 4; ++rr) {
      int n = rr * 16 + r;
      _Float16 o4[4];
#pragma unroll
      for (int j = 0; j < 4; ++j) o4[j] = (_Float16)tile[c4 + j][n];
      *(ushort4*)&dst[(size_t)(n0 + n) * Kd + k0 + c4] = *(ushort4*)o4;
    }
  } else if (blk < 1088) {
    int row = blk - 1024;   // 0..63
    if (row < 24) {
      int g = row >> 3, h = row & 7;
      int idx = (g == 0) ? 11 : ((g == 1) ? 13 : 15);
      const void* W = ip.p[idx];
      if (tid < 64) { int f = sniff_vote(W, ip.n[idx], tid); if (tid == 0) sfl[0] = f; }
      __syncthreads();
      int f = sfl[0];
#pragma unroll
      for (int it = 0; it < 4; ++it) {
        int d = it * 256 + tid;
        WgT[(size_t)row * Dim + d] = (_Float16)ldin(W, f, (size_t)d * Hh + h);
      }
    } else {
#pragma unroll
      for (int it = 0; it < 4; ++it)
        WgT[(size_t)row * Dim + it * 256 + tid] = (_Float16)0.f;
    }
  } else if (blk == 1088) {
    __shared__ int allf[17];
    for (int ii = 0; ii < 17; ++ii) {
      if (tid < 64) {
        int f = sniff_vote(ip.p[ii], ip.n[ii], tid);
        if (tid == 0) { flags[ii] = f; allf[ii] = f; }
      }
    }
    __syncthreads();
    int f9 = allf[9], f10 = allf[10];
    for (int i = tid; i < Di; i += 256) {
      gqf[i] = ldin(ip.p[9], f9, i);
      gkf[i] = ldin(ip.p[10], f10, i);
    }
    if (tid < 24) {
      int g = tid >> 3, h = tid & 7;
      int idx = (g == 0) ? 12 : ((g == 1) ? 14 : 16);
      gbf[tid] = ldin(ip.p[idx], allf[idx], h);
    }
  } else {
    // ---- rmsnorm + depthwise conv (self-contained) ----
    constexpr int NR = NT2 + 3;   // 11 rows: t0-2 .. t0+NT2
    _Float16 (*xas)[Dim] = (_Float16(*)[Dim])smem_u;

    int rb = blk - 1089;
    int tb = rb & 127, b = rb >> 7;
    int t0 = tb * NT2;
    int lane = tid & 63, wv = tid >> 6;

    if (tid < 64) {
      int f0 = sniff_vote(ip.p[0], ip.n[0], tid);
      int f1 = sniff_vote(ip.p[1], ip.n[1], tid);
      int f6 = sniff_vote(ip.p[6], ip.n[6], tid);
      int f7 = sniff_vote(ip.p[7], ip.n[7], tid);
      int f8 = sniff_vote(ip.p[8], ip.n[8], tid);
      if (tid == 0) { sfl[0] = f0; sfl[1] = f1; sfl[2] = f6; sfl[3] = f7; sfl[4] = f8; }
    }
    __syncthreads();
    int fx = sfl[0], fw = sfl[1], f6 = sfl[2], f7 = sfl[3], f8 = sfl[4];
    int e0 = lane * 16;

    float wr[16];
#pragma unroll
    for (int q = 0; q < 4; ++q) ld4(ip.p[1], fw, e0 + q * 4, &wr[q * 4]);

    for (int rr = wv; rr < NR; rr += 4) {
      int r = t0 - 2 + rr;
      float xv[16];
      bool inr = (r >= 0 && r < Seq);
      if (inr) {
        size_t rbx = (size_t)(b * Seq + r) * Dim + e0;
#pragma unroll
        for (int q = 0; q < 4; ++q) ld4(ip.p[0], fx, rbx + q * 4, &xv[q * 4]);
      } else {
#pragma unroll
        for (int j = 0; j < 16; ++j) xv[j] = 0.f;
      }
      float ss = 0.f;
#pragma unroll
      for (int j = 0; j < 16; ++j) ss = fmaf(xv[j], xv[j], ss);
#pragma unroll
      for (int m = 1; m < 64; m <<= 1) ss += __shfl_xor(ss, m);
      float scale = rsqrtf(ss * (1.0f / Dim) + EPSV);

      _Float16 o[16];
#pragma unroll
      for (int j = 0; j < 16; ++j) o[j] = (_Float16)(xv[j] * scale * wr[j]);
      *(uint4*)&xas[rr][e0]     = *(uint4*)&o[0];
      *(uint4*)&xas[rr][e0 + 8] = *(uint4*)&o[8];
      if (inr && r >= t0 && r < t0 + NT2) {
        size_t ob = (size_t)(b * Seq + r) * Dim + e0;
        *(uint4*)&xaf[ob]     = *(uint4*)&o[0];
        *(uint4*)&xaf[ob + 8] = *(uint4*)&o[8];
      }
    }
    __syncthreads();

    int c0 = tid * 4;
    float lwq[16], lwk[16], lwv[16];
#pragma unroll
    for (int q = 0; q < 4; ++q) {
      ld4(ip.p[6], f6, (size_t)c0 * 4 + q * 4, &lwq[q * 4]);
      ld4(ip.p[7], f7, (size_t)c0 * 4 + q * 4, &lwk[q * 4]);
      ld4(ip.p[8], f8, (size_t)c0 * 4 + q * 4, &lwv[q * 4]);
    }

#pragma unroll
    for (int tt = 0; tt < NT2; ++tt) {
      float rv[4][4];
#pragma unroll
      for (int k = 0; k < 4; ++k) {
        _Float16 hx[4];
        *(ushort4*)hx = *(const ushort4*)&xas[tt + k][c0];
#pragma unroll
        for (int j = 0; j < 4; ++j) rv[k][j] = (float)hx[j];
      }
      _Float16 tq[4], tk[4], tv[4];
#pragma unroll
      for (int j = 0; j < 4; ++j) {
        float aq = rv[0][j] * lwq[j * 4 + 0] + rv[1][j] * lwq[j * 4 + 1]
                 + rv[2][j] * lwq[j * 4 + 2] + rv[3][j] * lwq[j * 4 + 3];
        float ak = rv[0][j] * lwk[j * 4 + 0] + rv[1][j] * lwk[j * 4 + 1]
                 + rv[2][j] * lwk[j * 4 + 2] + rv[3][j] * lwk[j * 4 + 3];
        float av = rv[0][j] * lwv[j * 4 + 0] + rv[1][j] * lwv[j * 4 + 1]
                 + rv[2][j] * lwv[j * 4 + 2] + rv[3][j] * lwv[j * 4 + 3];
        tq[j] = (_Float16)aq; tk[j] = (_Float16)ak; tv[j] = (_Float16)av;
      }
      size_t o = ((size_t)(b * Seq + t0 + tt)) * Dim + c0;
      *(ushort4*)&qc[o] = *(ushort4*)tq;
      *(ushort4*)&kc[o] = *(ushort4*)tk;
      *(ushort4*)&vc[o] = *(ushort4*)tv;
    }
  }
}

// ---------------------------------------------------------------------------
// K_MID: QKV MFMA GEMM (128x128 tiles, global_load_lds) + gate GEMM partials.
// ---------------------------------------------------------------------------
__global__ __launch_bounds__(256) void k_mid(
    const _Float16* __restrict__ qc, const _Float16* __restrict__ kc,
    const _Float16* __restrict__ vc,
    const _Float16* __restrict__ wqT, const _Float16* __restrict__ wkT,
    const _Float16* __restrict__ wvT,
    const _Float16* __restrict__ xaf, const _Float16* __restrict__ WgT,
    _Float16* __restrict__ qpre, _Float16* __restrict__ kpre,
    _Float16* __restrict__ vpre,
    float* __restrict__ gpart)
{
  __shared__ __align__(16) _Float16 ldsbuf[256 * 32];   // 16 KB

  int blk = blockIdx.x;
  int tid = threadIdx.x, lane = tid & 63, wv = tid >> 6;
  int mrow = lane & 15, quad = lane >> 4;

  if (blk < 192) {
    int z = blk >> 6, rem = blk & 63;
    int by = rem >> 2, bx = rem & 3;
    const _Float16* A  = (z == 0) ? qc : ((z == 1) ? kc : vc);
    const _Float16* Bt = (z == 0) ? wqT : ((z == 1) ? wkT : wvT);
    _Float16* C        = (z == 0) ? qpre : ((z == 1) ? kpre : vpre);
    int m0 = by * 128, n0 = bx * 128;
    int wr = wv >> 1, wc = wv & 1;

    _Float16* Asl = ldsbuf;
    _Float16* Bsl = ldsbuf + 128 * 32;

    int sr = lane >> 2, sc = (lane & 3) * 8;

    f32x4 acc[4][4];
#pragma unroll
    for (int mi = 0; mi < 4; ++mi)
#pragma unroll
      for (int ni = 0; ni < 4; ++ni) acc[mi][ni] = (f32x4){0.f, 0.f, 0.f, 0.f};

    for (int kt = 0; kt < Dim; kt += 32) {
      __syncthreads();
      gld16(&A [(size_t)(m0 + wv * 32      + sr) * Dim + kt + sc], &Asl[(wv * 32     ) * 32]);
      gld16(&A [(size_t)(m0 + wv * 32 + 16 + sr) * Dim + kt + sc], &Asl[(wv * 32 + 16) * 32]);
      gld16(&Bt[(size_t)(n0 + wv * 32      + sr) * Dim + kt + sc], &Bsl[(wv * 32     ) * 32]);
      gld16(&Bt[(size_t)(n0 + wv * 32 + 16 + sr) * Dim + kt + sc], &Bsl[(wv * 32 + 16) * 32]);
      __syncthreads();

      half8 afr[4], bfr[4];
#pragma unroll
      for (int i = 0; i < 4; ++i)
        afr[i] = *(const half8*)&Asl[(wr * 64 + i * 16 + mrow) * 32 + quad * 8];
#pragma unroll
      for (int i = 0; i < 4; ++i)
        bfr[i] = *(const half8*)&Bsl[(wc * 64 + i * 16 + mrow) * 32 + quad * 8];
#pragma unroll
      for (int mi = 0; mi < 4; ++mi)
#pragma unroll
        for (int ni = 0; ni < 4; ++ni)
          acc[mi][ni] = __builtin_amdgcn_mfma_f32_16x16x32_f16(afr[mi], bfr[ni], acc[mi][ni], 0, 0, 0);
    }

#pragma unroll
    for (int mi = 0; mi < 4; ++mi) {
#pragma unroll
      for (int ni = 0; ni < 4; ++ni) {
        int col = n0 + wc * 64 + ni * 16 + mrow;
#pragma unroll
        for (int r2 = 0; r2 < 4; ++r2) {
          int row = m0 + wr * 64 + mi * 16 + quad * 4 + r2;
          C[(size_t)row * Di + col] = (_Float16)acc[mi][ni][r2];
        }
      }
    }
  } else {
    _Float16 (*As)[40] = (_Float16(*)[40])ldsbuf;
    _Float16 (*Bs)[40] = (_Float16(*)[40])(ldsbuf + 128 * 40);

    int g = blk - 192;
    int m0 = (g & 31) * 64, ks = g >> 5;
    int srow = tid >> 2, scol = (tid & 3) * 8;
    int kbase = ks * (Dim / KSPL);

    f32x4 acc[4];
#pragma unroll
    for (int mi = 0; mi < 4; ++mi) acc[mi] = (f32x4){0.f, 0.f, 0.f, 0.f};

    for (int kt = kbase; kt < kbase + Dim / KSPL; kt += 32) {
      __syncthreads();
      *(uint4*)&As[srow][scol] = *(const uint4*)&xaf[(size_t)(m0 + srow) * Dim + kt + scol];
      *(uint4*)&Bs[srow][scol] = *(const uint4*)&WgT[(size_t)srow * Dim + kt + scol];
      __syncthreads();
      half8 bfr = *(const half8*)&Bs[wv * 16 + mrow][quad * 8];
#pragma unroll
      for (int mi = 0; mi < 4; ++mi) {
        half8 afr = *(const half8*)&As[mi * 16 + mrow][quad * 8];
        acc[mi] = __builtin_amdgcn_mfma_f32_16x16x32_f16(afr, bfr, acc[mi], 0, 0, 0);
      }
    }

    int col = wv * 16 + mrow;          // only 0..23 real
    if (col < 24) {
#pragma unroll
      for (int mi = 0; mi < 4; ++mi) {
#pragma unroll
        for (int r2 = 0; r2 < 4; ++r2) {
          int row = m0 + mi * 16 + quad * 4 + r2;
          gpart[((size_t)ks * BN + row) * 32 + col] = acc[mi][r2];
        }
      }
    }
  }
}

// ---------------------------------------------------------------------------
// K3: final MFMA GEMM, 128M x 64N, global_load_lds staging, epilogue by flags.
// ---------------------------------------------------------------------------
__global__ __launch_bounds__(256) void k_gemm_fin(
    const _Float16* __restrict__ A, const _Float16* __restrict__ Bt,
    void* __restrict__ C, const int* __restrict__ flags, int Nn, int Kd)
{
  __shared__ __align__(16) _Float16 lds[(128 + 64) * 32];   // 12 KB
  _Float16* Asl = lds;                // [128][32] linear
  _Float16* Bsl = lds + 128 * 32;     // [64][32] linear

  int tid = threadIdx.x, lane = tid & 63, wv = tid >> 6;
  int n0 = blockIdx.x * 64, m0 = blockIdx.y * 128;
  int mrow = lane & 15, quad = lane >> 4;
  int wm = wv * 32;
  int sr = lane >> 2, sc = (lane & 3) * 8;

  f32x4 acc[2][4];
#pragma unroll
  for (int mi = 0; mi < 2; ++mi)
#pragma unroll
    for (int ni = 0; ni < 4; ++ni) acc[mi][ni] = (f32x4){0.f, 0.f, 0.f, 0.f};

  for (int kt = 0; kt < Kd; kt += 32) {
    __syncthreads();
    gld16(&A [(size_t)(m0 + wv * 32      + sr) * Kd + kt + sc], &Asl[(wv * 32     ) * 32]);
    gld16(&A [(size_t)(m0 + wv * 32 + 16 + sr) * Kd + kt + sc], &Asl[(wv * 32 + 16) * 32]);
    gld16(&Bt[(size_t)(n0 + wv * 16      + sr) * Kd + kt + sc], &Bsl[(wv * 16     ) * 32]);
    __syncthreads();

    half8 bfr[4];
#pragma unroll
    for (int ni = 0; ni < 4; ++ni)
      bfr[ni] = *(const half8*)&Bsl[(ni * 16 + mrow) * 32 + quad * 8];
#pragma unroll
    for (int mi = 0; mi < 2; ++mi) {
      half8 afr = *(const half8*)&Asl[(wm + mi * 16 + mrow) * 32 + quad * 8];
#pragma unroll
      for (int ni = 0; ni < 4; ++ni)
        acc[mi][ni] = __builtin_amdgcn_mfma_f32_16x16x32_f16(afr, bfr[ni], acc[mi][ni], 0, 0, 0);
    }
  }

  int any_bf16 = 0;
#pragma unroll
  for (int i2 = 0; i2 < 17; ++i2) any_bf16 |= (flags[i2] == 0);

#pragma unroll
  for (int mi = 0; mi < 2; ++mi) {
#pragma unroll
    for (int ni = 0; ni < 4; ++ni) {
      int col = n0 + ni * 16 + mrow;
#pragma unroll
      for (int r2 = 0; r2 < 4; ++r2) {
        int row = m0 + wm + mi * 16 + quad * 4 + r2;
        float v = acc[mi][ni][r2];
        size_t idx = (size_t)row * Nn + col;
        if (any_bf16) ((unsigned short*)C)[idx] = f2bf(v);
        else          ((float*)C)[idx] = v;
      }
    }
  }
}

// ---------------------------------------------------------------------------
// Gate preload helper: reduce KSPL partials + bias + sigmoid (96 threads)
// ---------------------------------------------------------------------------
DEV void load_gates(const float* __restrict__ gpart, const float* __restrict__ gbf,
                    int b, int h, int c, int tid,
                    float* gl, float* gd, float* gm)
{
  if (tid < 96) {
    int which = tid >> 5, t2 = tid & 31;
    int col = which * 8 + h;
    int row = b * Seq + c * CLEN + t2;
    float acc = gbf[col];
#pragma unroll
    for (int ks = 0; ks < KSPL; ++ks)
      acc += gpart[((size_t)ks * BN + row) * 32 + col];
    float sg = 1.f / (1.f + expf(-acc));
    if (which == 0) gl[t2] = sg; else if (which == 1) gd[t2] = sg; else gm[t2] = sg;
  }
}

// ---------------------------------------------------------------------------
// Recurrence phases. phaseA writes NORMALIZED k back to kpre, so phaseC
// skips the k-norm pass entirely.
// ---------------------------------------------------------------------------
__global__ __launch_bounds__(256) void k_phaseA(
    _Float16* __restrict__ kpre, const _Float16* __restrict__ vpre,
    const float* __restrict__ gkf,
    const float* __restrict__ gpart, const float* __restrict__ gbf,
    _Float16* __restrict__ ZS_Z, _Float16* __restrict__ ZS_S,
    float* __restrict__ Mc, float* __restrict__ Dc, float* __restrict__ Wc)
{
  int c = blockIdx.x, s = blockIdx.y;
  int b = s >> 3, h = s & 7;
  int tid = threadIdx.x, lane = tid & 63, wv = tid >> 6;
  int i = tid >> 2, j0 = (tid & 3) * 16;
  __shared__ float kn[CLEN][64], vv[CLEN][64];
  __shared__ float gl[CLEN], gd[CLEN], gm[CLEN];

  {
    int t = tid >> 3, col = (tid & 7) * 8;
    size_t g = ((size_t)(b * Seq + c * CLEN + t)) * Di + h * 64 + col;
    half8 kv = *(const half8*)&kpre[g];
    half8 vvv = *(const half8*)&vpre[g];
#pragma unroll
    for (int j = 0; j < 8; ++j) { kn[t][col + j] = (float)kv[j]; vv[t][col + j] = (float)vvv[j]; }
    load_gates(gpart, gbf, b, h, c, tid, gl, gd, gm);
  }
  __syncthreads();
  {
    float gk = gkf[h * 64 + lane];
#pragma unroll
    for (int tt = 0; tt < 8; ++tt) {
      int t = wv * 8 + tt;
      float kvv = kn[t][lane];
      float ss = kvv * kvv;
#pragma unroll
      for (int m = 1; m < 64; m <<= 1) ss += __shfl_xor(ss, m);
      float knv = kvv * (1.f / fmaxf(sqrtf(ss) * 0.125f, 1e-8f)) * gk;
      kn[t][lane] = knv;
      // write normalized k back so phaseC can skip the norm pass
      kpre[((size_t)(b * Seq + c * CLEN + t)) * Di + h * 64 + lane] = (_Float16)knv;
    }
  }
  __syncthreads();

  float Zl[16], Sl[16];
#pragma unroll
  for (int jj = 0; jj < 16; ++jj) { Zl[jj] = 0.f; Sl[jj] = 0.f; }
  float Mcum = 1.f, Dcum = 1.f, wacc = 0.f;

  for (int t = 0; t < CLEN; ++t) {
    float l = gl[t], dd = gd[t], mm = gm[t];
    float vi = vv[t][i];
    Mcum *= mm;
#pragma unroll
    for (int jj = 0; jj < 16; ++jj) {
      Zl[jj] = fmaf(mm, Zl[jj], -vi * kn[t][j0 + jj]);
      Sl[jj] = fmaf(dd, Sl[jj], -l * Zl[jj]);
    }
    wacc = fmaf(dd, wacc, -l * Mcum);
    Dcum *= dd;
  }
  size_t base = ((size_t)(s * CHUNK + c)) * 4096 + (size_t)i * 64 + j0;
  half8 zo0, zo1, so0, so1;
#pragma unroll
  for (int jj = 0; jj < 8; ++jj) {
    zo0[jj] = (_Float16)Zl[jj];     zo1[jj] = (_Float16)Zl[jj + 8];
    so0[jj] = (_Float16)Sl[jj];     so1[jj] = (_Float16)Sl[jj + 8];
  }
  *(half8*)&ZS_Z[base] = zo0; *(half8*)&ZS_Z[base + 8] = zo1;
  *(half8*)&ZS_S[base] = so0; *(half8*)&ZS_S[base + 8] = so1;
  if (tid == 0) {
    Mc[s * CHUNK + c] = Mcum; Dc[s * CHUNK + c] = Dcum; Wc[s * CHUNK + c] = wacc;
  }
}

// ---------------------------------------------------------------------------
// K_PHASEB (LDS-staged): block = (s, 128-wide e-slice). All chunk loads are
// issued in parallel (coalesced half8), serial scan runs against LDS, then
// cooperative write-back. Removes the per-iteration HBM dependency chain.
// ---------------------------------------------------------------------------
__global__ __launch_bounds__(256) void k_phaseB(
    _Float16* __restrict__ ZS_Z, _Float16* __restrict__ ZS_S,
    const float* __restrict__ Mc, const float* __restrict__ Dc,
    const float* __restrict__ Wc)
{
  int s = blockIdx.x;
  int e0 = blockIdx.y * 128;
  int tid = threadIdx.x;
  __shared__ _Float16 zbuf[CHUNK][128], sbuf[CHUNK][128];   // 8 KB each
  __shared__ float gms[3][CHUNK];

  // cooperative load: 2 rounds x 256 threads x half8 covers 32c x 128e
  {
#pragma unroll
    for (int r = 0; r < 2; ++r) {
      int idx = r * 256 + tid;           // 0..511
      int c = idx >> 4, es = (idx & 15) * 8;
      size_t g = ((size_t)(s * CHUNK + c)) * 4096 + e0 + es;
      *(half8*)&zbuf[c][es] = *(const half8*)&ZS_Z[g];
      *(half8*)&sbuf[c][es] = *(const half8*)&ZS_S[g];
    }
    if (tid < 96) {
      int w = tid >> 5, c = tid & 31;
      const float* src = (w == 0) ? Mc : ((w == 1) ? Dc : Wc);
      gms[w][c] = src[s * CHUNK + c];
    }
  }
  __syncthreads();

  // serial scan per e (threads 0..127 active)
  if (tid < 128) {
    float Z = 0.f, S = 0.f;
#pragma unroll
    for (int c = 0; c < CHUNK; ++c) {
      float zl = (float)zbuf[c][tid], sl = (float)sbuf[c][tid];
      zbuf[c][tid] = (_Float16)Z; sbuf[c][tid] = (_Float16)S;   // chunk inputs
      float mc = gms[0][c], dc = gms[1][c], wc = gms[2][c];
      S = fmaf(dc, S, fmaf(wc, Z, sl));  // uses OLD Z (= chunk input)
      Z = fmaf(mc, Z, zl);
    }
  }
  __syncthreads();

  // cooperative write-back
#pragma unroll
  for (int r = 0; r < 2; ++r) {
    int idx = r * 256 + tid;
    int c = idx >> 4, es = (idx & 15) * 8;
    size_t g = ((size_t)(s * CHUNK + c)) * 4096 + e0 + es;
    *(half8*)&ZS_Z[g] = *(const half8*)&zbuf[c][es];
    *(half8*)&ZS_S[g] = *(const half8*)&sbuf[c][es];
  }
}

__global__ __launch_bounds__(256) void k_phaseC(
    const _Float16* __restrict__ qpre, const _Float16* __restrict__ kpre,
    const _Float16* __restrict__ vpre,
    const float* __restrict__ gqf,
    const float* __restrict__ gpart, const float* __restrict__ gbf,
    const _Float16* __restrict__ ZS_Z, const _Float16* __restrict__ ZS_S,
    _Float16* __restrict__ yb)
{
  int c = blockIdx.x, s = blockIdx.y;
  int b = s >> 3, h = s & 7;
  int tid = threadIdx.x, lane = tid & 63, wv = tid >> 6;
  int i = tid >> 2, j0 = (tid & 3) * 16;
  __shared__ float kn[CLEN][64], vv[CLEN][64], qn[CLEN][64];
  __shared__ float gl[CLEN], gd[CLEN], gm[CLEN];

  float Zi_[16], Si_[16], Zl[16], Sl[16];
  size_t base = ((size_t)(s * CHUNK + c)) * 4096 + (size_t)i * 64 + j0;
  {
    half8 z0 = *(const half8*)&ZS_Z[base], z1 = *(const half8*)&ZS_Z[base + 8];
    half8 s0 = *(const half8*)&ZS_S[base], s1 = *(const half8*)&ZS_S[base + 8];
#pragma unroll
    for (int jj = 0; jj < 8; ++jj) {
      Zi_[jj] = (float)z0[jj]; Zi_[jj + 8] = (float)z1[jj];
      Si_[jj] = (float)s0[jj]; Si_[jj + 8] = (float)s1[jj];
      Zl[jj] = 0.f; Zl[jj + 8] = 0.f; Sl[jj] = 0.f; Sl[jj + 8] = 0.f;
    }
  }
  {
    int t = tid >> 3, col = (tid & 7) * 8;
    size_t g = ((size_t)(b * Seq + c * CLEN + t)) * Di + h * 64 + col;
    half8 kv = *(const half8*)&kpre[g];   // already normalized (phaseA)
    half8 vvv = *(const half8*)&vpre[g];
    half8 qv = *(const half8*)&qpre[g];
#pragma unroll
    for (int j = 0; j < 8; ++j) {
      kn[t][col + j] = (float)kv[j]; vv[t][col + j] = (float)vvv[j];
      qn[t][col + j] = (float)qv[j];
    }
    load_gates(gpart, gbf, b, h, c, tid, gl, gd, gm);
  }
  __syncthreads();
  {
    float gq = gqf[h * 64 + lane];
#pragma unroll
    for (int tt = 0; tt < 8; ++tt) {
      int t = wv * 8 + tt;
      float qvv = qn[t][lane];
      float ssq = qvv * qvv;
#pragma unroll
      for (int m = 1; m < 64; m <<= 1) ssq += __shfl_xor(ssq, m);
      qn[t][lane] = qvv * (1.f / fmaxf(sqrtf(ssq) * 0.125f, 1e-8f)) * gq;
    }
  }
  __syncthreads();

  float Mcum = 1.f, Dcum = 1.f, wacc = 0.f;
  float Dprev = 1.f, wprev = 0.f;

  for (int t = 0; t < CLEN; ++t) {
    float l = gl[t], dd = gd[t], mm = gm[t];

    float yp = 0.f;
#pragma unroll
    for (int jj = 0; jj < 16; ++jj) {
      float tmp = fmaf(Dprev, Si_[jj], fmaf(wprev, Zi_[jj], Sl[jj]));
      yp = fmaf(tmp, qn[t][j0 + jj], yp);
    }
    yp += __shfl_xor(yp, 1);
    yp += __shfl_xor(yp, 2);
    if ((tid & 3) == 0)
      yb[((size_t)(b * Seq + c * CLEN + t)) * Di + h * 64 + i] = (_Float16)yp;

    float vi = vv[t][i];
    Mcum *= mm;
#pragma unroll
    for (int jj = 0; jj < 16; ++jj) {
      Zl[jj] = fmaf(mm, Zl[jj], -vi * kn[t][j0 + jj]);
      Sl[jj] = fmaf(dd, Sl[jj], -l * Zl[jj]);
    }
    wacc = fmaf(dd, wacc, -l * Mcum);
    Dcum *= dd;
    Dprev = Dcum; wprev = wacc;
  }
}

// ---------------------------------------------------------------------------
extern "C" void kernel_launch(void* const* d_in, const int* in_sizes, int n_in,
                              void* d_out, int out_size, void* d_ws, size_t ws_size,
                              hipStream_t stream) {
  InPtrs ip;
  for (int i = 0; i < 17; ++i) { ip.p[i] = d_in[i]; ip.n[i] = in_sizes[i]; }

  char* p = (char*)d_ws;
  auto take = [&](size_t bytes) -> char* {
    char* q = p; p += (bytes + 255) & ~(size_t)255; return q;
  };
  int* flags           = (int*)take(32 * 4);
  _Float16* xaf        = (_Float16*)take((size_t)BN * Dim * 2);   // 4 MB
  _Float16* qc         = (_Float16*)take((size_t)BN * Dim * 2);   // 4 MB
  _Float16* kc         = (_Float16*)take((size_t)BN * Dim * 2);   // 4 MB
  _Float16* vc         = (_Float16*)take((size_t)BN * Dim * 2);   // 4 MB
  _Float16* qpre       = (_Float16*)take((size_t)BN * Di * 2);    // 2 MB
  _Float16* kpre       = (_Float16*)take((size_t)BN * Di * 2);    // 2 MB
  _Float16* vpre       = (_Float16*)take((size_t)BN * Di * 2);    // 2 MB
  float* gpart         = (float*)take((size_t)KSPL * BN * 32 * 4); // 2 MB
  float* Mc            = (float*)take((size_t)NSEQ * CHUNK * 4);
  float* Dc            = (float*)take((size_t)NSEQ * CHUNK * 4);
  float* Wc            = (float*)take((size_t)NSEQ * CHUNK * 4);
  _Float16* wqT        = (_Float16*)take((size_t)Di * Dim * 2);   // 1 MB
  _Float16* wkT        = (_Float16*)take((size_t)Di * Dim * 2);   // 1 MB
  _Float16* wvT        = (_Float16*)take((size_t)Di * Dim * 2);   // 1 MB
  _Float16* woT        = (_Float16*)take((size_t)Dim * Di * 2);   // 1 MB
  _Float16* WgT        = (_Float16*)take((size_t)64 * Dim * 2);   // 128 KB
  float* gqf           = (float*)take(Di * 4);
  float* gkf           = (float*)take(Di * 4);
  float* gbf           = (float*)take(32 * 4);
  // Aliases: qc/kc/vc are dead after k_mid
  _Float16* ZS_Z       = qc;
  _Float16* ZS_S       = kc;
  _Float16* yb         = vc;

  k_front<<<1345, 256, 0, stream>>>(ip, flags, wqT, wkT, wvT, woT, WgT,
                                    gqf, gkf, gbf, xaf, qc, kc, vc);

  k_mid<<<448, 256, 0, stream>>>(qc, kc, vc, wqT, wkT, wvT, xaf, WgT,
                                 qpre, kpre, vpre, gpart);

  k_phaseA<<<dim3(CHUNK, NSEQ), 256, 0, stream>>>(kpre, vpre, gkf,
                                                  gpart, gbf,
                                                  ZS_Z, ZS_S, Mc, Dc, Wc);
  k_phaseB<<<dim3(NSEQ, 4096 / 128), 256, 0, stream>>>(ZS_Z, ZS_S, Mc, Dc, Wc);
  k_phaseC<<<dim3(CHUNK, NSEQ), 256, 0, stream>>>(qpre, kpre, vpre, gqf,
                                                  gpart, gbf,
                                                  ZS_Z, ZS_S, yb);

  k_gemm_fin<<<dim3(Dim / 64, BN / 128), 256, 0, stream>>>(
      yb, woT, d_out, flags, Dim, Di);
}

// Round 6
// 177.982 us; speedup vs baseline: 1.0447x; 1.0082x over previous
//
#include <hip/hip_runtime.h>
#include <math.h>

#define DEV __device__ __forceinline__

constexpr int Bb   = 2;
constexpr int Seq  = 1024;
constexpr int Dim  = 1024;
constexpr int Hh   = 8;
constexpr int Dh   = 64;
constexpr int Di   = 512;
constexpr int BN   = Bb * Seq;       // 2048
constexpr int NSEQ = Bb * Hh;        // 16
constexpr int CHUNK = 32;            // chunks per sequence
constexpr int CLEN  = Seq / CHUNK;   // 32
constexpr float EPSV = 1.1920929e-07f;
constexpr int NT2  = 8;              // conv timesteps per block (fused kernel)
constexpr int KSPL = 8;              // gate GEMM K-splits

typedef _Float16 half8 __attribute__((ext_vector_type(8)));
typedef float    f32x4 __attribute__((ext_vector_type(4)));

DEV float bf2f(unsigned short u) {
  union { unsigned int i; float f; } x; x.i = ((unsigned int)u) << 16; return x.f;
}
DEV unsigned short f2bf(float f) {
  union { float f; unsigned int i; } x; x.f = f;
  unsigned int r = x.i + 0x7fffu + ((x.i >> 16) & 1u);
  return (unsigned short)(r >> 16);
}
// flag: 1 -> fp32, 0 -> bf16
DEV float ldin(const void* p, int f32, size_t i) {
  if (f32) return ((const float*)p)[i];
  return bf2f(((const unsigned short*)p)[i]);
}
DEV void ld4(const void* p, int f32, size_t i, float* dst) {
  if (f32) {
    float4 u = *(const float4*)((const float*)p + i);
    dst[0] = u.x; dst[1] = u.y; dst[2] = u.z; dst[3] = u.w;
  } else {
    ushort4 u = *(const ushort4*)((const unsigned short*)p + i);
    dst[0] = bf2f(u.x); dst[1] = bf2f(u.y); dst[2] = bf2f(u.z); dst[3] = bf2f(u.w);
  }
}
// per-thread sample vote for self-sniff (call with tid<64, reduce in wave)
DEV int sniff_vote(const void* p, int n, int tid) {
  int j = 2 * tid, valid = 0, bad = 0;
  if (j < n) {
    valid = 1;
    float v = bf2f(((const unsigned short*)p)[j]);
    float a = fabsf(v);
    if (!(a >= 1e-12f && a <= 1e4f)) bad = 1;
  }
#pragma unroll
  for (int m = 1; m < 64; m <<= 1) { valid += __shfl_xor(valid, m); bad += __shfl_xor(bad, m); }
  return (2 * bad > valid) ? 1 : 0;
}

// async global->LDS: 16 bytes per lane, LDS dest = wave-uniform base + lane*16
DEV void gld16(const _Float16* g, _Float16* l) {
  __builtin_amdgcn_global_load_lds(
      (const __attribute__((address_space(1))) void*)g,
      (__attribute__((address_space(3))) void*)l, 16, 0, 0);
}

struct InPtrs { const void* p[17]; int n[17]; };

// ---------------------------------------------------------------------------
// K_FRONT: weight prep + fused RMSNorm/conv in one launch (independent roles).
//   [0,1024)    : transpose+convert wq/wk/wv/wo -> f16 [N][K]
//   [1024,1088) : gate weights -> WgT[64][1024]
//   1088        : full flags[17] + gammas + gate biases
//   [1089,1345) : rmsnorm+conv blocks (self-sniffed, raw conv weights)
// ---------------------------------------------------------------------------
__global__ __launch_bounds__(256) void k_front(
    InPtrs ip,
    int* __restrict__ flags,
    _Float16* __restrict__ wqT, _Float16* __restrict__ wkT,
    _Float16* __restrict__ wvT, _Float16* __restrict__ woT,
    _Float16* __restrict__ WgT,
    float* __restrict__ gqf, float* __restrict__ gkf, float* __restrict__ gbf,
    _Float16* __restrict__ xaf,
    _Float16* __restrict__ qc, _Float16* __restrict__ kc,
    _Float16* __restrict__ vc)
{
  int blk = blockIdx.x;
  int tid = threadIdx.x;
  __shared__ int sfl[8];
  __shared__ __align__(16) char smem_u[11 * Dim * 2];   // 22528 B union

  if (blk < 1024) {
    int z = blk >> 8, bx = blk & 15, by = (blk >> 4) & 15;
    int idx = (z == 0) ? 2 : ((z == 1) ? 3 : ((z == 2) ? 4 : 5));
    const void* src = ip.p[idx];
    _Float16* dst   = (z == 0) ? wqT : ((z == 1) ? wkT : ((z == 2) ? wvT : woT));
    int Kd = (z < 3) ? Dim : Di;
    int Nn = (z < 3) ? Di : Dim;
    int n0 = bx * 64, k0 = by * 64;
    if (n0 >= Nn || k0 >= Kd) return;

    if (tid < 64) { int f = sniff_vote(src, ip.n[idx], tid); if (tid == 0) sfl[0] = f; }
    __syncthreads();
    int f = sfl[0];

    float (*tile)[65] = (float(*)[65])smem_u;   // 64x65 floats = 16640 B
    int r = tid >> 4, c4 = (tid & 15) * 4;
#pragma unroll
    for (int rr = 0; rr < 4; ++rr) {
      int k = rr * 16 + r;
      ld4(src, f, (size_t)(k0 + k) * Nn + n0 + c4, &tile[k][c4]);
    }
    __syncthreads();
#pragma unroll
    for (int rr = 0; rr < 4; ++rr) {
      int n = rr * 16 + r;
      _Float16 o4[4];
#pragma unroll
      for (int j = 0; j < 4; ++j) o4[j] = (_Float16)tile[c4 + j][n];
      *(ushort4*)&dst[(size_t)(n0 + n) * Kd + k0 + c4] = *(ushort4*)o4;
    }
  } else if (blk < 1088) {
    int row = blk - 1024;   // 0..63
    if (row < 24) {
      int g = row >> 3, h = row & 7;
      int idx = (g == 0) ? 11 : ((g == 1) ? 13 : 15);
      const void* W = ip.p[idx];
      if (tid < 64) { int f = sniff_vote(W, ip.n[idx], tid); if (tid == 0) sfl[0] = f; }
      __syncthreads();
      int f = sfl[0];
#pragma unroll
      for (int it = 0; it < 4; ++it) {
        int d = it * 256 + tid;
        WgT[(size_t)row * Dim + d] = (_Float16)ldin(W, f, (size_t)d * Hh + h);
      }
    } else {
#pragma unroll
      for (int it = 0; it < 4; ++it)
        WgT[(size_t)row * Dim + it * 256 + tid] = (_Float16)0.f;
    }
  } else if (blk == 1088) {
    __shared__ int allf[17];
    for (int ii = 0; ii < 17; ++ii) {
      if (tid < 64) {
        int f = sniff_vote(ip.p[ii], ip.n[ii], tid);
        if (tid == 0) { flags[ii] = f; allf[ii] = f; }
      }
    }
    __syncthreads();
    int f9 = allf[9], f10 = allf[10];
    for (int i = tid; i < Di; i += 256) {
      gqf[i] = ldin(ip.p[9], f9, i);
      gkf[i] = ldin(ip.p[10], f10, i);
    }
    if (tid < 24) {
      int g = tid >> 3, h = tid & 7;
      int idx = (g == 0) ? 12 : ((g == 1) ? 14 : 16);
      gbf[tid] = ldin(ip.p[idx], allf[idx], h);
    }
  } else {
    // ---- rmsnorm + depthwise conv (self-contained) ----
    constexpr int NR = NT2 + 3;   // 11 rows: t0-2 .. t0+NT2
    _Float16 (*xas)[Dim] = (_Float16(*)[Dim])smem_u;

    int rb = blk - 1089;
    int tb = rb & 127, b = rb >> 7;
    int t0 = tb * NT2;
    int lane = tid & 63, wv = tid >> 6;

    if (tid < 64) {
      int f0 = sniff_vote(ip.p[0], ip.n[0], tid);
      int f1 = sniff_vote(ip.p[1], ip.n[1], tid);
      int f6 = sniff_vote(ip.p[6], ip.n[6], tid);
      int f7 = sniff_vote(ip.p[7], ip.n[7], tid);
      int f8 = sniff_vote(ip.p[8], ip.n[8], tid);
      if (tid == 0) { sfl[0] = f0; sfl[1] = f1; sfl[2] = f6; sfl[3] = f7; sfl[4] = f8; }
    }
    __syncthreads();
    int fx = sfl[0], fw = sfl[1], f6 = sfl[2], f7 = sfl[3], f8 = sfl[4];
    int e0 = lane * 16;

    float wr[16];
#pragma unroll
    for (int q = 0; q < 4; ++q) ld4(ip.p[1], fw, e0 + q * 4, &wr[q * 4]);

    for (int rr = wv; rr < NR; rr += 4) {
      int r = t0 - 2 + rr;
      float xv[16];
      bool inr = (r >= 0 && r < Seq);
      if (inr) {
        size_t rbx = (size_t)(b * Seq + r) * Dim + e0;
#pragma unroll
        for (int q = 0; q < 4; ++q) ld4(ip.p[0], fx, rbx + q * 4, &xv[q * 4]);
      } else {
#pragma unroll
        for (int j = 0; j < 16; ++j) xv[j] = 0.f;
      }
      float ss = 0.f;
#pragma unroll
      for (int j = 0; j < 16; ++j) ss = fmaf(xv[j], xv[j], ss);
#pragma unroll
      for (int m = 1; m < 64; m <<= 1) ss += __shfl_xor(ss, m);
      float scale = rsqrtf(ss * (1.0f / Dim) + EPSV);

      _Float16 o[16];
#pragma unroll
      for (int j = 0; j < 16; ++j) o[j] = (_Float16)(xv[j] * scale * wr[j]);
      *(uint4*)&xas[rr][e0]     = *(uint4*)&o[0];
      *(uint4*)&xas[rr][e0 + 8] = *(uint4*)&o[8];
      if (inr && r >= t0 && r < t0 + NT2) {
        size_t ob = (size_t)(b * Seq + r) * Dim + e0;
        *(uint4*)&xaf[ob]     = *(uint4*)&o[0];
        *(uint4*)&xaf[ob + 8] = *(uint4*)&o[8];
      }
    }
    __syncthreads();

    int c0 = tid * 4;
    float lwq[16], lwk[16], lwv[16];
#pragma unroll
    for (int q = 0; q < 4; ++q) {
      ld4(ip.p[6], f6, (size_t)c0 * 4 + q * 4, &lwq[q * 4]);
      ld4(ip.p[7], f7, (size_t)c0 * 4 + q * 4, &lwk[q * 4]);
      ld4(ip.p[8], f8, (size_t)c0 * 4 + q * 4, &lwv[q * 4]);
    }

#pragma unroll
    for (int tt = 0; tt < NT2; ++tt) {
      float rv[4][4];
#pragma unroll
      for (int k = 0; k < 4; ++k) {
        _Float16 hx[4];
        *(ushort4*)hx = *(const ushort4*)&xas[tt + k][c0];
#pragma unroll
        for (int j = 0; j < 4; ++j) rv[k][j] = (float)hx[j];
      }
      _Float16 tq[4], tk[4], tv[4];
#pragma unroll
      for (int j = 0; j < 4; ++j) {
        float aq = rv[0][j] * lwq[j * 4 + 0] + rv[1][j] * lwq[j * 4 + 1]
                 + rv[2][j] * lwq[j * 4 + 2] + rv[3][j] * lwq[j * 4 + 3];
        float ak = rv[0][j] * lwk[j * 4 + 0] + rv[1][j] * lwk[j * 4 + 1]
                 + rv[2][j] * lwk[j * 4 + 2] + rv[3][j] * lwk[j * 4 + 3];
        float av = rv[0][j] * lwv[j * 4 + 0] + rv[1][j] * lwv[j * 4 + 1]
                 + rv[2][j] * lwv[j * 4 + 2] + rv[3][j] * lwv[j * 4 + 3];
        tq[j] = (_Float16)aq; tk[j] = (_Float16)ak; tv[j] = (_Float16)av;
      }
      size_t o = ((size_t)(b * Seq + t0 + tt)) * Dim + c0;
      *(ushort4*)&qc[o] = *(ushort4*)tq;
      *(ushort4*)&kc[o] = *(ushort4*)tk;
      *(ushort4*)&vc[o] = *(ushort4*)tv;
    }
  }
}

// ---------------------------------------------------------------------------
// K_MID: QKV MFMA GEMM (128x128 tiles, BK=64, global_load_lds) + gate GEMM.
// BK=64 halves the per-block barrier/vmcnt-drain count (QKV runs at ~1
// block/CU, so intra-block drain stalls are unhidden — fewer is faster).
// ---------------------------------------------------------------------------
__global__ __launch_bounds__(256) void k_mid(
    const _Float16* __restrict__ qc, const _Float16* __restrict__ kc,
    const _Float16* __restrict__ vc,
    const _Float16* __restrict__ wqT, const _Float16* __restrict__ wkT,
    const _Float16* __restrict__ wvT,
    const _Float16* __restrict__ xaf, const _Float16* __restrict__ WgT,
    _Float16* __restrict__ qpre, _Float16* __restrict__ kpre,
    _Float16* __restrict__ vpre,
    float* __restrict__ gpart)
{
  __shared__ __align__(16) _Float16 ldsbuf[256 * 64];   // 32 KB

  int blk = blockIdx.x;
  int tid = threadIdx.x, lane = tid & 63, wv = tid >> 6;
  int mrow = lane & 15, quad = lane >> 4;

  if (blk < 192) {
    int z = blk >> 6, rem = blk & 63;
    int by = rem >> 2, bx = rem & 3;
    const _Float16* A  = (z == 0) ? qc : ((z == 1) ? kc : vc);
    const _Float16* Bt = (z == 0) ? wqT : ((z == 1) ? wkT : wvT);
    _Float16* C        = (z == 0) ? qpre : ((z == 1) ? kpre : vpre);
    int m0 = by * 128, n0 = bx * 128;
    int wr = wv >> 1, wc = wv & 1;

    _Float16* Asl = ldsbuf;              // [128][64] linear
    _Float16* Bsl = ldsbuf + 128 * 64;   // [128][64] linear

    int sr8 = lane >> 3;        // 8 rows per gld16 (row = 64 elem = 128 B)
    int sc8 = (lane & 7) * 8;

    f32x4 acc[4][4];
#pragma unroll
    for (int mi = 0; mi < 4; ++mi)
#pragma unroll
      for (int ni = 0; ni < 4; ++ni) acc[mi][ni] = (f32x4){0.f, 0.f, 0.f, 0.f};

    for (int kt = 0; kt < Dim; kt += 64) {
      __syncthreads();
      // wave wv stages A rows [wv*32, wv*32+32) and B rows [wv*32, wv*32+32)
#pragma unroll
      for (int u = 0; u < 4; ++u) {
        int r0 = wv * 32 + u * 8;
        gld16(&A [(size_t)(m0 + r0 + sr8) * Dim + kt + sc8], &Asl[r0 * 64]);
        gld16(&Bt[(size_t)(n0 + r0 + sr8) * Dim + kt + sc8], &Bsl[r0 * 64]);
      }
      __syncthreads();

#pragma unroll
      for (int kh = 0; kh < 2; ++kh) {
        half8 afr[4], bfr[4];
#pragma unroll
        for (int i = 0; i < 4; ++i)
          afr[i] = *(const half8*)&Asl[(wr * 64 + i * 16 + mrow) * 64 + kh * 32 + quad * 8];
#pragma unroll
        for (int i = 0; i < 4; ++i)
          bfr[i] = *(const half8*)&Bsl[(wc * 64 + i * 16 + mrow) * 64 + kh * 32 + quad * 8];
#pragma unroll
        for (int mi = 0; mi < 4; ++mi)
#pragma unroll
          for (int ni = 0; ni < 4; ++ni)
            acc[mi][ni] = __builtin_amdgcn_mfma_f32_16x16x32_f16(afr[mi], bfr[ni], acc[mi][ni], 0, 0, 0);
      }
    }

#pragma unroll
    for (int mi = 0; mi < 4; ++mi) {
#pragma unroll
      for (int ni = 0; ni < 4; ++ni) {
        int col = n0 + wc * 64 + ni * 16 + mrow;
#pragma unroll
        for (int r2 = 0; r2 < 4; ++r2) {
          int row = m0 + wr * 64 + mi * 16 + quad * 4 + r2;
          C[(size_t)row * Di + col] = (_Float16)acc[mi][ni][r2];
        }
      }
    }
  } else {
    _Float16 (*As)[40] = (_Float16(*)[40])ldsbuf;
    _Float16 (*Bs)[40] = (_Float16(*)[40])(ldsbuf + 128 * 40);

    int g = blk - 192;
    int m0 = (g & 31) * 64, ks = g >> 5;
    int srow = tid >> 2, scol = (tid & 3) * 8;
    int kbase = ks * (Dim / KSPL);

    f32x4 acc[4];
#pragma unroll
    for (int mi = 0; mi < 4; ++mi) acc[mi] = (f32x4){0.f, 0.f, 0.f, 0.f};

    for (int kt = kbase; kt < kbase + Dim / KSPL; kt += 32) {
      __syncthreads();
      *(uint4*)&As[srow][scol] = *(const uint4*)&xaf[(size_t)(m0 + srow) * Dim + kt + scol];
      *(uint4*)&Bs[srow][scol] = *(const uint4*)&WgT[(size_t)srow * Dim + kt + scol];
      __syncthreads();
      half8 bfr = *(const half8*)&Bs[wv * 16 + mrow][quad * 8];
#pragma unroll
      for (int mi = 0; mi < 4; ++mi) {
        half8 afr = *(const half8*)&As[mi * 16 + mrow][quad * 8];
        acc[mi] = __builtin_amdgcn_mfma_f32_16x16x32_f16(afr, bfr, acc[mi], 0, 0, 0);
      }
    }

    int col = wv * 16 + mrow;          // only 0..23 real
    if (col < 24) {
#pragma unroll
      for (int mi = 0; mi < 4; ++mi) {
#pragma unroll
        for (int r2 = 0; r2 < 4; ++r2) {
          int row = m0 + mi * 16 + quad * 4 + r2;
          gpart[((size_t)ks * BN + row) * 32 + col] = acc[mi][r2];
        }
      }
    }
  }
}

// ---------------------------------------------------------------------------
// K3: final MFMA GEMM, 64M x 64N tiles (512 blocks = 2/CU so barrier drains
// of co-resident blocks interleave), gld16 staging, epilogue dtype by flags.
// ---------------------------------------------------------------------------
__global__ __launch_bounds__(256) void k_gemm_fin(
    const _Float16* __restrict__ A, const _Float16* __restrict__ Bt,
    void* __restrict__ C, const int* __restrict__ flags, int Nn, int Kd)
{
  __shared__ __align__(16) _Float16 lds[(64 + 64) * 32];   // 8 KB
  _Float16* Asl = lds;                // [64][32] linear
  _Float16* Bsl = lds + 64 * 32;      // [64][32] linear

  int tid = threadIdx.x, lane = tid & 63, wv = tid >> 6;
  int n0 = blockIdx.x * 64, m0 = blockIdx.y * 64;
  int mrow = lane & 15, quad = lane >> 4;
  int wr = wv >> 1, wc = wv & 1;
  int sr = lane >> 2, sc = (lane & 3) * 8;   // 16 rows per gld16

  f32x4 acc[2][2];
#pragma unroll
  for (int mi = 0; mi < 2; ++mi)
#pragma unroll
    for (int ni = 0; ni < 2; ++ni) acc[mi][ni] = (f32x4){0.f, 0.f, 0.f, 0.f};

  for (int kt = 0; kt < Kd; kt += 32) {
    __syncthreads();
    gld16(&A [(size_t)(m0 + wv * 16 + sr) * Kd + kt + sc], &Asl[(wv * 16) * 32]);
    gld16(&Bt[(size_t)(n0 + wv * 16 + sr) * Kd + kt + sc], &Bsl[(wv * 16) * 32]);
    __syncthreads();

    half8 afr[2], bfr[2];
#pragma unroll
    for (int i2 = 0; i2 < 2; ++i2) {
      afr[i2] = *(const half8*)&Asl[(wr * 32 + i2 * 16 + mrow) * 32 + quad * 8];
      bfr[i2] = *(const half8*)&Bsl[(wc * 32 + i2 * 16 + mrow) * 32 + quad * 8];
    }
#pragma unroll
    for (int mi = 0; mi < 2; ++mi)
#pragma unroll
      for (int ni = 0; ni < 2; ++ni)
        acc[mi][ni] = __builtin_amdgcn_mfma_f32_16x16x32_f16(afr[mi], bfr[ni], acc[mi][ni], 0, 0, 0);
  }

  int any_bf16 = 0;
#pragma unroll
  for (int i2 = 0; i2 < 17; ++i2) any_bf16 |= (flags[i2] == 0);

#pragma unroll
  for (int mi = 0; mi < 2; ++mi) {
#pragma unroll
    for (int ni = 0; ni < 2; ++ni) {
      int col = n0 + wc * 32 + ni * 16 + mrow;
#pragma unroll
      for (int r2 = 0; r2 < 4; ++r2) {
        int row = m0 + wr * 32 + mi * 16 + quad * 4 + r2;
        float v = acc[mi][ni][r2];
        size_t idx = (size_t)row * Nn + col;
        if (any_bf16) ((unsigned short*)C)[idx] = f2bf(v);
        else          ((float*)C)[idx] = v;
      }
    }
  }
}

// ---------------------------------------------------------------------------
// Gate preload helper: reduce KSPL partials + bias + sigmoid (96 threads)
// ---------------------------------------------------------------------------
DEV void load_gates(const float* __restrict__ gpart, const float* __restrict__ gbf,
                    int b, int h, int c, int tid,
                    float* gl, float* gd, float* gm)
{
  if (tid < 96) {
    int which = tid >> 5, t2 = tid & 31;
    int col = which * 8 + h;
    int row = b * Seq + c * CLEN + t2;
    float acc = gbf[col];
#pragma unroll
    for (int ks = 0; ks < KSPL; ++ks)
      acc += gpart[((size_t)ks * BN + row) * 32 + col];
    float sg = 1.f / (1.f + expf(-acc));
    if (which == 0) gl[t2] = sg; else if (which == 1) gd[t2] = sg; else gm[t2] = sg;
  }
}

// ---------------------------------------------------------------------------
// Recurrence phases. phaseA writes NORMALIZED k back to kpre, so phaseC
// skips the k-norm pass entirely.
// ---------------------------------------------------------------------------
__global__ __launch_bounds__(256) void k_phaseA(
    _Float16* __restrict__ kpre, const _Float16* __restrict__ vpre,
    const float* __restrict__ gkf,
    const float* __restrict__ gpart, const float* __restrict__ gbf,
    _Float16* __restrict__ ZS_Z, _Float16* __restrict__ ZS_S,
    float* __restrict__ Mc, float* __restrict__ Dc, float* __restrict__ Wc)
{
  int c = blockIdx.x, s = blockIdx.y;
  int b = s >> 3, h = s & 7;
  int tid = threadIdx.x, lane = tid & 63, wv = tid >> 6;
  int i = tid >> 2, j0 = (tid & 3) * 16;
  __shared__ float kn[CLEN][64], vv[CLEN][64];
  __shared__ float gl[CLEN], gd[CLEN], gm[CLEN];

  {
    int t = tid >> 3, col = (tid & 7) * 8;
    size_t g = ((size_t)(b * Seq + c * CLEN + t)) * Di + h * 64 + col;
    half8 kv = *(const half8*)&kpre[g];
    half8 vvv = *(const half8*)&vpre[g];
#pragma unroll
    for (int j = 0; j < 8; ++j) { kn[t][col + j] = (float)kv[j]; vv[t][col + j] = (float)vvv[j]; }
    load_gates(gpart, gbf, b, h, c, tid, gl, gd, gm);
  }
  __syncthreads();
  {
    float gk = gkf[h * 64 + lane];
#pragma unroll
    for (int tt = 0; tt < 8; ++tt) {
      int t = wv * 8 + tt;
      float kvv = kn[t][lane];
      float ss = kvv * kvv;
#pragma unroll
      for (int m = 1; m < 64; m <<= 1) ss += __shfl_xor(ss, m);
      float knv = kvv * (1.f / fmaxf(sqrtf(ss) * 0.125f, 1e-8f)) * gk;
      kn[t][lane] = knv;
      // write normalized k back so phaseC can skip the norm pass
      kpre[((size_t)(b * Seq + c * CLEN + t)) * Di + h * 64 + lane] = (_Float16)knv;
    }
  }
  __syncthreads();

  float Zl[16], Sl[16];
#pragma unroll
  for (int jj = 0; jj < 16; ++jj) { Zl[jj] = 0.f; Sl[jj] = 0.f; }
  float Mcum = 1.f, Dcum = 1.f, wacc = 0.f;

  for (int t = 0; t < CLEN; ++t) {
    float l = gl[t], dd = gd[t], mm = gm[t];
    float vi = vv[t][i];
    Mcum *= mm;
#pragma unroll
    for (int jj = 0; jj < 16; ++jj) {
      Zl[jj] = fmaf(mm, Zl[jj], -vi * kn[t][j0 + jj]);
      Sl[jj] = fmaf(dd, Sl[jj], -l * Zl[jj]);
    }
    wacc = fmaf(dd, wacc, -l * Mcum);
    Dcum *= dd;
  }
  size_t base = ((size_t)(s * CHUNK + c)) * 4096 + (size_t)i * 64 + j0;
  half8 zo0, zo1, so0, so1;
#pragma unroll
  for (int jj = 0; jj < 8; ++jj) {
    zo0[jj] = (_Float16)Zl[jj];     zo1[jj] = (_Float16)Zl[jj + 8];
    so0[jj] = (_Float16)Sl[jj];     so1[jj] = (_Float16)Sl[jj + 8];
  }
  *(half8*)&ZS_Z[base] = zo0; *(half8*)&ZS_Z[base + 8] = zo1;
  *(half8*)&ZS_S[base] = so0; *(half8*)&ZS_S[base + 8] = so1;
  if (tid == 0) {
    Mc[s * CHUNK + c] = Mcum; Dc[s * CHUNK + c] = Dcum; Wc[s * CHUNK + c] = wacc;
  }
}

// ---------------------------------------------------------------------------
// K_PHASEB (LDS-staged): block = (s, 128-wide e-slice). All chunk loads are
// issued in parallel (coalesced half8), serial scan runs against LDS, then
// cooperative write-back. Removes the per-iteration HBM dependency chain.
// ---------------------------------------------------------------------------
__global__ __launch_bounds__(256) void k_phaseB(
    _Float16* __restrict__ ZS_Z, _Float16* __restrict__ ZS_S,
    const float* __restrict__ Mc, const float* __restrict__ Dc,
    const float* __restrict__ Wc)
{
  int s = blockIdx.x;
  int e0 = blockIdx.y * 128;
  int tid = threadIdx.x;
  __shared__ _Float16 zbuf[CHUNK][128], sbuf[CHUNK][128];   // 8 KB each
  __shared__ float gms[3][CHUNK];

  // cooperative load: 2 rounds x 256 threads x half8 covers 32c x 128e
  {
#pragma unroll
    for (int r = 0; r < 2; ++r) {
      int idx = r * 256 + tid;           // 0..511
      int c = idx >> 4, es = (idx & 15) * 8;
      size_t g = ((size_t)(s * CHUNK + c)) * 4096 + e0 + es;
      *(half8*)&zbuf[c][es] = *(const half8*)&ZS_Z[g];
      *(half8*)&sbuf[c][es] = *(const half8*)&ZS_S[g];
    }
    if (tid < 96) {
      int w = tid >> 5, c = tid & 31;
      const float* src = (w == 0) ? Mc : ((w == 1) ? Dc : Wc);
      gms[w][c] = src[s * CHUNK + c];
    }
  }
  __syncthreads();

  // serial scan per e (threads 0..127 active)
  if (tid < 128) {
    float Z = 0.f, S = 0.f;
#pragma unroll
    for (int c = 0; c < CHUNK; ++c) {
      float zl = (float)zbuf[c][tid], sl = (float)sbuf[c][tid];
      zbuf[c][tid] = (_Float16)Z; sbuf[c][tid] = (_Float16)S;   // chunk inputs
      float mc = gms[0][c], dc = gms[1][c], wc = gms[2][c];
      S = fmaf(dc, S, fmaf(wc, Z, sl));  // uses OLD Z (= chunk input)
      Z = fmaf(mc, Z, zl);
    }
  }
  __syncthreads();

  // cooperative write-back
#pragma unroll
  for (int r = 0; r < 2; ++r) {
    int idx = r * 256 + tid;
    int c = idx >> 4, es = (idx & 15) * 8;
    size_t g = ((size_t)(s * CHUNK + c)) * 4096 + e0 + es;
    *(half8*)&ZS_Z[g] = *(const half8*)&zbuf[c][es];
    *(half8*)&ZS_S[g] = *(const half8*)&sbuf[c][es];
  }
}

__global__ __launch_bounds__(256) void k_phaseC(
    const _Float16* __restrict__ qpre, const _Float16* __restrict__ kpre,
    const _Float16* __restrict__ vpre,
    const float* __restrict__ gqf,
    const float* __restrict__ gpart, const float* __restrict__ gbf,
    const _Float16* __restrict__ ZS_Z, const _Float16* __restrict__ ZS_S,
    _Float16* __restrict__ yb)
{
  int c = blockIdx.x, s = blockIdx.y;
  int b = s >> 3, h = s & 7;
  int tid = threadIdx.x, lane = tid & 63, wv = tid >> 6;
  int i = tid >> 2, j0 = (tid & 3) * 16;
  __shared__ float kn[CLEN][64], vv[CLEN][64], qn[CLEN][64];
  __shared__ float gl[CLEN], gd[CLEN], gm[CLEN];

  float Zi_[16], Si_[16], Zl[16], Sl[16];
  size_t base = ((size_t)(s * CHUNK + c)) * 4096 + (size_t)i * 64 + j0;
  {
    half8 z0 = *(const half8*)&ZS_Z[base], z1 = *(const half8*)&ZS_Z[base + 8];
    half8 s0 = *(const half8*)&ZS_S[base], s1 = *(const half8*)&ZS_S[base + 8];
#pragma unroll
    for (int jj = 0; jj < 8; ++jj) {
      Zi_[jj] = (float)z0[jj]; Zi_[jj + 8] = (float)z1[jj];
      Si_[jj] = (float)s0[jj]; Si_[jj + 8] = (float)s1[jj];
      Zl[jj] = 0.f; Zl[jj + 8] = 0.f; Sl[jj] = 0.f; Sl[jj + 8] = 0.f;
    }
  }
  {
    int t = tid >> 3, col = (tid & 7) * 8;
    size_t g = ((size_t)(b * Seq + c * CLEN + t)) * Di + h * 64 + col;
    half8 kv = *(const half8*)&kpre[g];   // already normalized (phaseA)
    half8 vvv = *(const half8*)&vpre[g];
    half8 qv = *(const half8*)&qpre[g];
#pragma unroll
    for (int j = 0; j < 8; ++j) {
      kn[t][col + j] = (float)kv[j]; vv[t][col + j] = (float)vvv[j];
      qn[t][col + j] = (float)qv[j];
    }
    load_gates(gpart, gbf, b, h, c, tid, gl, gd, gm);
  }
  __syncthreads();
  {
    float gq = gqf[h * 64 + lane];
#pragma unroll
    for (int tt = 0; tt < 8; ++tt) {
      int t = wv * 8 + tt;
      float qvv = qn[t][lane];
      float ssq = qvv * qvv;
#pragma unroll
      for (int m = 1; m < 64; m <<= 1) ssq += __shfl_xor(ssq, m);
      qn[t][lane] = qvv * (1.f / fmaxf(sqrtf(ssq) * 0.125f, 1e-8f)) * gq;
    }
  }
  __syncthreads();

  float Mcum = 1.f, Dcum = 1.f, wacc = 0.f;
  float Dprev = 1.f, wprev = 0.f;

  for (int t = 0; t < CLEN; ++t) {
    float l = gl[t], dd = gd[t], mm = gm[t];

    float yp = 0.f;
#pragma unroll
    for (int jj = 0; jj < 16; ++jj) {
      float tmp = fmaf(Dprev, Si_[jj], fmaf(wprev, Zi_[jj], Sl[jj]));
      yp = fmaf(tmp, qn[t][j0 + jj], yp);
    }
    yp += __shfl_xor(yp, 1);
    yp += __shfl_xor(yp, 2);
    if ((tid & 3) == 0)
      yb[((size_t)(b * Seq + c * CLEN + t)) * Di + h * 64 + i] = (_Float16)yp;

    float vi = vv[t][i];
    Mcum *= mm;
#pragma unroll
    for (int jj = 0; jj < 16; ++jj) {
      Zl[jj] = fmaf(mm, Zl[jj], -vi * kn[t][j0 + jj]);
      Sl[jj] = fmaf(dd, Sl[jj], -l * Zl[jj]);
    }
    wacc = fmaf(dd, wacc, -l * Mcum);
    Dcum *= dd;
    Dprev = Dcum; wprev = wacc;
  }
}

// ---------------------------------------------------------------------------
extern "C" void kernel_launch(void* const* d_in, const int* in_sizes, int n_in,
                              void* d_out, int out_size, void* d_ws, size_t ws_size,
                              hipStream_t stream) {
  InPtrs ip;
  for (int i = 0; i < 17; ++i) { ip.p[i] = d_in[i]; ip.n[i] = in_sizes[i]; }

  char* p = (char*)d_ws;
  auto take = [&](size_t bytes) -> char* {
    char* q = p; p += (bytes + 255) & ~(size_t)255; return q;
  };
  int* flags           = (int*)take(32 * 4);
  _Float16* xaf        = (_Float16*)take((size_t)BN * Dim * 2);   // 4 MB
  _Float16* qc         = (_Float16*)take((size_t)BN * Dim * 2);   // 4 MB
  _Float16* kc         = (_Float16*)take((size_t)BN * Dim * 2);   // 4 MB
  _Float16* vc         = (_Float16*)take((size_t)BN * Dim * 2);   // 4 MB
  _Float16* qpre       = (_Float16*)take((size_t)BN * Di * 2);    // 2 MB
  _Float16* kpre       = (_Float16*)take((size_t)BN * Di * 2);    // 2 MB
  _Float16* vpre       = (_Float16*)take((size_t)BN * Di * 2);    // 2 MB
  float* gpart         = (float*)take((size_t)KSPL * BN * 32 * 4); // 2 MB
  float* Mc            = (float*)take((size_t)NSEQ * CHUNK * 4);
  float* Dc            = (float*)take((size_t)NSEQ * CHUNK * 4);
  float* Wc            = (float*)take((size_t)NSEQ * CHUNK * 4);
  _Float16* wqT        = (_Float16*)take((size_t)Di * Dim * 2);   // 1 MB
  _Float16* wkT        = (_Float16*)take((size_t)Di * Dim * 2);   // 1 MB
  _Float16* wvT        = (_Float16*)take((size_t)Di * Dim * 2);   // 1 MB
  _Float16* woT        = (_Float16*)take((size_t)Dim * Di * 2);   // 1 MB
  _Float16* WgT        = (_Float16*)take((size_t)64 * Dim * 2);   // 128 KB
  float* gqf           = (float*)take(Di * 4);
  float* gkf           = (float*)take(Di * 4);
  float* gbf           = (float*)take(32 * 4);
  // Aliases: qc/kc/vc are dead after k_mid
  _Float16* ZS_Z       = qc;
  _Float16* ZS_S       = kc;
  _Float16* yb         = vc;

  k_front<<<1345, 256, 0, stream>>>(ip, flags, wqT, wkT, wvT, woT, WgT,
                                    gqf, gkf, gbf, xaf, qc, kc, vc);

  k_mid<<<448, 256, 0, stream>>>(qc, kc, vc, wqT, wkT, wvT, xaf, WgT,
                                 qpre, kpre, vpre, gpart);

  k_phaseA<<<dim3(CHUNK, NSEQ), 256, 0, stream>>>(kpre, vpre, gkf,
                                                  gpart, gbf,
                                                  ZS_Z, ZS_S, Mc, Dc, Wc);
  k_phaseB<<<dim3(NSEQ, 4096 / 128), 256, 0, stream>>>(ZS_Z, ZS_S, Mc, Dc, Wc);
  k_phaseC<<<dim3(CHUNK, NSEQ), 256, 0, stream>>>(qpre, kpre, vpre, gqf,
                                                  gpart, gbf,
                                                  ZS_Z, ZS_S, yb);

  k_gemm_fin<<<dim3(Dim / 64, BN / 64), 256, 0, stream>>>(
      yb, woT, d_out, flags, Dim, Di);
}